// Round 3
// baseline (333.028 us; speedup 1.0000x reference)
//
#include <hip/hip_runtime.h>
#include <math.h>

#define NFFT   2048
#define LOG2N  11
#define BB     8
#define WW     32
#define MM     16
#define NLAYER 4

// Padded LDS index: +1 float per 32 -> breaks power-of-2 bank aliasing
#define PAD(i) ((i) + ((i) >> 5))
#define PADDED_N (NFFT + (NFFT >> 5))   // 2112

// ---------- fast gelu (exact-erf form, A&S 7.1.26, |err| <= 1.5e-7) ----------
__device__ __forceinline__ float gelu_f(float v) {
    float ax = fabsf(v) * 0.70710678118654752440f;
    float t  = __builtin_amdgcn_rcpf(fmaf(0.3275911f, ax, 1.0f));
    float s  = fmaf(1.061405429f, t, -1.453152027f);
    s = fmaf(s, t, 1.421413741f);
    s = fmaf(s, t, -0.284496736f);
    s = fmaf(s, t, 0.254829592f);
    s = s * t;
    float e  = __expf(-ax * ax);
    float er = fmaf(-s, e, 1.0f);          // erf(|v|/sqrt2)
    er = copysignf(er, v);
    return 0.5f * v * (1.0f + er);
}

// ---------- complex helpers ----------
__device__ __forceinline__ float2 cadd(float2 a, float2 b) { return make_float2(a.x + b.x, a.y + b.y); }
__device__ __forceinline__ float2 csub(float2 a, float2 b) { return make_float2(a.x - b.x, a.y - b.y); }
__device__ __forceinline__ float2 cmul(float2 a, float2 b) {
    return make_float2(fmaf(a.x, b.x, -a.y * b.y), fmaf(a.x, b.y, a.y * b.x));
}
// a + S*i*b  /  a - S*i*b   (S=-1 forward FFT, S=+1 inverse)
template<int S> __device__ __forceinline__ float2 caddi(float2 a, float2 b) {
    return (S > 0) ? make_float2(a.x - b.y, a.y + b.x) : make_float2(a.x + b.y, a.y - b.x);
}
template<int S> __device__ __forceinline__ float2 csubi(float2 a, float2 b) {
    return (S > 0) ? make_float2(a.x + b.y, a.y - b.x) : make_float2(a.x - b.y, a.y + b.x);
}

template<int S> __device__ __forceinline__ void dft4(float2* a) {
    float2 t0 = cadd(a[0], a[2]), t1 = csub(a[0], a[2]);
    float2 t2 = cadd(a[1], a[3]), t3 = csub(a[1], a[3]);
    a[0] = cadd(t0, t2);
    a[2] = csub(t0, t2);
    a[1] = caddi<S>(t1, t3);
    a[3] = csubi<S>(t1, t3);
}

template<int S> __device__ __forceinline__ void dft8(float2* a) {
    const float c = 0.70710678118654752440f;
    float2 t0 = cadd(a[0], a[4]), t1 = csub(a[0], a[4]);
    float2 t2 = cadd(a[2], a[6]), t3 = csub(a[2], a[6]);
    float2 u0 = cadd(a[1], a[5]), u1 = csub(a[1], a[5]);
    float2 u2 = cadd(a[3], a[7]), u3 = csub(a[3], a[7]);
    float2 e0 = cadd(t0, t2), e2 = csub(t0, t2);
    float2 e1 = caddi<S>(t1, t3), e3 = csubi<S>(t1, t3);
    float2 o0 = cadd(u0, u2), o2 = csub(u0, u2);
    float2 o1 = caddi<S>(u1, u3), o3 = csubi<S>(u1, u3);
    float2 w1o, w2o, w3o;
    if (S < 0) {  // forward: w1=c(1-i), w2=-i, w3=c(-1-i)
        w1o = make_float2(c * (o1.x + o1.y), c * (o1.y - o1.x));
        w2o = make_float2(o2.y, -o2.x);
        w3o = make_float2(c * (o3.y - o3.x), c * (-o3.y - o3.x));
    } else {      // inverse: conjugates
        w1o = make_float2(c * (o1.x - o1.y), c * (o1.y + o1.x));
        w2o = make_float2(-o2.y, o2.x);
        w3o = make_float2(c * (-o3.x - o3.y), c * (o3.x - o3.y));
    }
    a[0] = cadd(e0, o0);  a[4] = csub(e0, o0);
    a[1] = cadd(e1, w1o); a[5] = csub(e1, w1o);
    a[2] = cadd(e2, w2o); a[6] = csub(e2, w2o);
    a[3] = cadd(e3, w3o); a[7] = csub(e3, w3o);
}

// ---------- Stockham autosort passes (N=2048, 256 threads) ----------
// pass: for j in [0,N/R): s=j%Ls, q=j/Ls; a_r = in[j + r*N/R];
//       a_r *= W_{R*Ls}^{S* r*s}; b = DFT_R(a); out[q*R*Ls + r*Ls + s] = b_r
template<int LS, int S>
__device__ __forceinline__ void pass_r8(const float* sre, const float* sim,
                                        float* dre, float* dim, int t) {
    const int s = t & (LS - 1);
    const int q = t / LS;
    float2 a[8];
    #pragma unroll
    for (int r = 0; r < 8; ++r) {
        int idx = t + r * 256;
        a[r] = make_float2(sre[PAD(idx)], sim[PAD(idx)]);
    }
    if (LS > 1) {
        float ph = (6.2831853071795864769f / (8.0f * (float)LS)) * (float)s;
        float sn, cs;
        __sincosf(ph, &sn, &cs);
        float2 w1 = make_float2(cs, (S > 0) ? sn : -sn);
        float2 wr = w1;
        a[1] = cmul(a[1], w1);
        #pragma unroll
        for (int r = 2; r < 8; ++r) { wr = cmul(wr, w1); a[r] = cmul(a[r], wr); }
    }
    dft8<S>(a);
    int base = q * (8 * LS) + s;
    #pragma unroll
    for (int r = 0; r < 8; ++r) {
        int idx = base + r * LS;
        dre[PAD(idx)] = a[r].x;
        dim[PAD(idx)] = a[r].y;
    }
}

template<int S>
__device__ __forceinline__ void pass_r4_512(const float* sre, const float* sim,
                                            float* dre, float* dim, int t) {
    #pragma unroll
    for (int h = 0; h < 2; ++h) {
        int j = t + h * 256;        // = s (q=0)
        float2 a[4];
        #pragma unroll
        for (int r = 0; r < 4; ++r) {
            int idx = j + r * 512;
            a[r] = make_float2(sre[PAD(idx)], sim[PAD(idx)]);
        }
        float ph = (6.2831853071795864769f / 2048.0f) * (float)j;
        float sn, cs;
        __sincosf(ph, &sn, &cs);
        float2 w1 = make_float2(cs, (S > 0) ? sn : -sn);
        a[1] = cmul(a[1], w1);
        float2 w2 = cmul(w1, w1);
        a[2] = cmul(a[2], w2);
        a[3] = cmul(a[3], cmul(w2, w1));
        dft4<S>(a);
        #pragma unroll
        for (int r = 0; r < 4; ++r) {
            int idx = r * 512 + j;
            dre[PAD(idx)] = a[r].x;
            dim[PAD(idx)] = a[r].y;
        }
    }
}

// In: natural order in A (padded). Out: natural order in A. Caller syncs before.
template<int S>
__device__ __forceinline__ void fft2048(float* Ar, float* Ai, float* Br, float* Bi, int t) {
    pass_r8<1, S>(Ar, Ai, Br, Bi, t);  __syncthreads();
    pass_r8<8, S>(Br, Bi, Ar, Ai, t);  __syncthreads();
    pass_r8<64, S>(Ar, Ai, Br, Bi, t); __syncthreads();
    pass_r4_512<S>(Br, Bi, Ar, Ai, t); __syncthreads();
}

// ---------- K0: h = gelu(fc0([x,grid])), forward FFT -> alpha ----------
__global__ __launch_bounds__(256) void k_fc0_fft(
    const float* __restrict__ x, const float* __restrict__ fc0_w,
    const float* __restrict__ fc0_b, float2* __restrict__ alpha)
{
    __shared__ float Ar[PADDED_N], Ai[PADDED_N], Br[PADDED_N], Bi[PADDED_N];
    int t = threadIdx.x;
    int row = blockIdx.x;            // b*32 + w
    int b = row >> 5, w = row & 31;
    float w0 = fc0_w[2 * w], w1 = fc0_w[2 * w + 1], b0 = fc0_b[w];
    #pragma unroll
    for (int j = 0; j < 8; ++j) {
        int idx = t + j * 256;
        float xv = x[b * NFFT + idx];
        float gv = (float)idx * (1.0f / 2047.0f);
        float val = gelu_f(fmaf(w0, xv, fmaf(w1, gv, b0)));
        Ar[PAD(idx)] = val;
        Ai[PAD(idx)] = 0.0f;
    }
    __syncthreads();
    fft2048<-1>(Ar, Ai, Br, Bi, t);
    #pragma unroll
    for (int j = 0; j < 8; ++j) {
        int k = t + j * 256;
        alpha[row * NFFT + k] = make_float2(Ar[PAD(k)], Ai[PAD(k)]);
    }
}

// ---------- K2: fused transfer function + channel einsum ----------
// H[i,o,k] = sum_m res/(lam_k - pole) + conv_w[o,i] + spec-fold(k)
// Y[b,o,k] = sum_i alpha[b,i,k]*H[i,o,k]  (+ L*conv_b[o] at k==0)
// 1024 thr, 4 k/block, grid 512 -> 2 blocks/CU, 32 waves/CU.
__global__ __launch_bounds__(1024, 8) void k_apply(
    const float2* __restrict__ alpha, float2* __restrict__ Y,
    const float* __restrict__ pole_re, const float* __restrict__ pole_im,
    const float* __restrict__ res_re,  const float* __restrict__ res_im,
    const float* __restrict__ spec_re, const float* __restrict__ spec_im,
    const float* __restrict__ conv_w,  const float* __restrict__ conv_b,
    const float* __restrict__ tgrid, int layer)
{
    __shared__ float2 s_hw[WW][4][33];   // [o][kk][i], i padded
    int t = threadIdx.x;
    int k0 = blockIdx.x * 4;
    float dt = tgrid[1] - tgrid[0];
    float fscale = 6.2831853071795864769f / ((float)NFFT * dt);
    int i = t & 31, o = t >> 5;
    float fk[4];
    #pragma unroll
    for (int kk = 0; kk < 4; ++kk) {
        int k = k0 + kk;
        int ks = (k < NFFT / 2) ? k : k - NFFT;
        fk[kk] = fscale * (float)ks;
    }
    int pb = ((layer * WW + i) * WW + o) * MM;
    float cw = conv_w[(layer * WW + o) * WW + i];
    float2 acc[4];
    #pragma unroll
    for (int kk = 0; kk < 4; ++kk) acc[kk] = make_float2(cw, 0.0f);
    #pragma unroll
    for (int mq = 0; mq < 4; ++mq) {
        float4 P_re = *(const float4*)&pole_re[pb + 4 * mq];
        float4 P_im = *(const float4*)&pole_im[pb + 4 * mq];
        float4 R_re = *(const float4*)&res_re [pb + 4 * mq];
        float4 R_im = *(const float4*)&res_im [pb + 4 * mq];
        #pragma unroll
        for (int mm = 0; mm < 4; ++mm) {
            float pr = (&P_re.x)[mm], pi = (&P_im.x)[mm];
            float rr = (&R_re.x)[mm], ri = (&R_im.x)[mm];
            float c  = -pr;
            float c2 = c * c;
            float rc = rr * c;
            float ic = ri * c;
            #pragma unroll
            for (int kk = 0; kk < 4; ++kk) {
                float d   = fk[kk] - pi;
                float inv = __builtin_amdgcn_rcpf(fmaf(d, d, c2));
                acc[kk].x = fmaf(fmaf(ri, d, rc), inv, acc[kk].x);
                acc[kk].y = fmaf(fmaf(-rr, d, ic), inv, acc[kk].y);
            }
        }
    }
    if (k0 < MM || k0 >= NFFT - MM) {     // spectral-conv fold (4 of 512 blocks)
        #pragma unroll
        for (int kk = 0; kk < 4; ++kk) {
            int k = k0 + kk;
            if (k < MM) {
                acc[kk].x += spec_re[pb + k];
                acc[kk].y += spec_im[pb + k];
            } else if (k > NFFT - MM) {   // conj bins (alpha Hermitian)
                acc[kk].x += spec_re[pb + NFFT - k];
                acc[kk].y -= spec_im[pb + NFFT - k];
            }
        }
    }
    #pragma unroll
    for (int kk = 0; kk < 4; ++kk) s_hw[o][kk][i] = acc[kk];
    __syncthreads();

    // Phase 2: one (b,o,k) per thread.
    int kl = t & 3, o2 = (t >> 2) & 31, bq = t >> 7;
    int k = k0 + kl;
    float2 a2 = make_float2(0.0f, 0.0f);
    const float2* ab = alpha + (size_t)(bq * WW) * NFFT + k;
    #pragma unroll 8
    for (int ii = 0; ii < 32; ++ii) {
        float2 hh = s_hw[o2][kl][ii];
        float2 av = ab[ii * NFFT];
        a2.x = fmaf(av.x, hh.x, fmaf(-av.y, hh.y, a2.x));
        a2.y = fmaf(av.x, hh.y, fmaf( av.y, hh.x, a2.y));
    }
    if (k == 0) a2.x += (float)NFFT * conv_b[layer * WW + o2];
    Y[(bq * WW + o2) * NFFT + k] = a2;
}

// ---------- K4: ifft -> Re/N -> gelu -> (forward fft | store h) ----------
template<bool LAST>
__global__ __launch_bounds__(256) void k_ifft_gelu_fft(
    const float2* __restrict__ Y, float2* __restrict__ alpha,
    float* __restrict__ hout)
{
    __shared__ float Ar[PADDED_N], Ai[PADDED_N], Br[PADDED_N], Bi[PADDED_N];
    int t = threadIdx.x;
    int row = blockIdx.x;
    #pragma unroll
    for (int j = 0; j < 8; ++j) {
        int k = t + j * 256;
        float2 v = Y[row * NFFT + k];
        Ar[PAD(k)] = v.x;
        Ai[PAD(k)] = v.y;
    }
    __syncthreads();
    fft2048<1>(Ar, Ai, Br, Bi, t);        // unnormalized inverse
    float vals[8];
    #pragma unroll
    for (int j = 0; j < 8; ++j) {
        int l = t + j * 256;
        vals[j] = gelu_f(Ar[PAD(l)] * (1.0f / (float)NFFT));
    }
    if (LAST) {
        #pragma unroll
        for (int j = 0; j < 8; ++j) hout[row * NFFT + t + j * 256] = vals[j];
    } else {
        __syncthreads();                  // all reads of Ar done
        #pragma unroll
        for (int j = 0; j < 8; ++j) {
            int idx = t + j * 256;
            Ar[PAD(idx)] = vals[j];
            Ai[PAD(idx)] = 0.0f;
        }
        __syncthreads();
        fft2048<-1>(Ar, Ai, Br, Bi, t);
        #pragma unroll
        for (int j = 0; j < 8; ++j) {
            int k = t + j * 256;
            alpha[row * NFFT + k] = make_float2(Ar[PAD(k)], Ai[PAD(k)]);
        }
    }
}

// ---------- K5: head. 4 waves/block, wave = n-group (uniform n -> LDS bcast) --
__global__ __launch_bounds__(256) void k_head(
    const float* __restrict__ h, const float* __restrict__ fc1_w,
    const float* __restrict__ fc1_b, const float* __restrict__ fc2_w,
    const float* __restrict__ fc2_b, float* __restrict__ out)
{
    __shared__ float s_w1[128 * 32];
    __shared__ float s_b1[128];
    __shared__ float s_w2[128];
    __shared__ float s_part[4][64];
    int t = threadIdx.x;
    for (int j = t; j < 128 * 32; j += 256) s_w1[j] = fc1_w[j];
    if (t < 128) { s_b1[t] = fc1_b[t]; s_w2[t] = fc2_w[t]; }
    __syncthreads();
    int wv  = t >> 6;                       // wave id = n-group
    int ln  = t & 63;
    int pos = blockIdx.x * 64 + ln;         // b*2048 + l
    int b = pos >> LOG2N, l = pos & (NFFT - 1);
    float hreg[32];
    #pragma unroll
    for (int w = 0; w < 32; ++w) hreg[w] = h[(b * WW + w) * NFFT + l];
    float acc = 0.0f;
    int n0 = wv * 32;
    for (int n = n0; n < n0 + 32; ++n) {
        float a = s_b1[n];
        #pragma unroll
        for (int w = 0; w < 32; w += 4) {
            float4 ww = *(const float4*)&s_w1[n * 32 + w];
            a = fmaf(ww.x, hreg[w],     a);
            a = fmaf(ww.y, hreg[w + 1], a);
            a = fmaf(ww.z, hreg[w + 2], a);
            a = fmaf(ww.w, hreg[w + 3], a);
        }
        acc = fmaf(s_w2[n], gelu_f(a), acc);
    }
    s_part[wv][ln] = acc;
    __syncthreads();
    if (t < 64) {
        float r = s_part[0][t] + s_part[1][t] + s_part[2][t] + s_part[3][t] + fc2_b[0];
        out[blockIdx.x * 64 + t] = r;
    }
}

extern "C" void kernel_launch(void* const* d_in, const int* in_sizes, int n_in,
                              void* d_out, int out_size, void* d_ws, size_t ws_size,
                              hipStream_t stream)
{
    const float* x       = (const float*)d_in[0];
    const float* tg      = (const float*)d_in[1];
    const float* fc0_w   = (const float*)d_in[2];
    const float* fc0_b   = (const float*)d_in[3];
    const float* pole_re = (const float*)d_in[4];
    const float* pole_im = (const float*)d_in[5];
    const float* res_re  = (const float*)d_in[6];
    const float* res_im  = (const float*)d_in[7];
    const float* spec_re = (const float*)d_in[8];
    const float* spec_im = (const float*)d_in[9];
    const float* conv_w  = (const float*)d_in[10];
    const float* conv_b  = (const float*)d_in[11];
    const float* fc1_w   = (const float*)d_in[12];
    const float* fc1_b   = (const float*)d_in[13];
    const float* fc2_w   = (const float*)d_in[14];
    const float* fc2_b   = (const float*)d_in[15];
    float* out = (float*)d_out;

    char* ws = (char*)d_ws;
    const size_t plane = (size_t)(BB * WW) * NFFT * sizeof(float2);  // 4 MiB
    float2* alpha = (float2*)ws;
    float2* Yb    = (float2*)(ws + plane);
    float*  hbuf  = (float*)(ws + 2 * plane);

    hipLaunchKernelGGL(k_fc0_fft, dim3(BB * WW), dim3(256), 0, stream,
                       x, fc0_w, fc0_b, alpha);
    for (int layer = 0; layer < NLAYER; ++layer) {
        hipLaunchKernelGGL(k_apply, dim3(NFFT / 4), dim3(1024), 0, stream,
                           alpha, Yb, pole_re, pole_im, res_re, res_im,
                           spec_re, spec_im, conv_w, conv_b, tg, layer);
        if (layer < NLAYER - 1)
            hipLaunchKernelGGL((k_ifft_gelu_fft<false>), dim3(BB * WW), dim3(256),
                               0, stream, Yb, alpha, (float*)nullptr);
        else
            hipLaunchKernelGGL((k_ifft_gelu_fft<true>), dim3(BB * WW), dim3(256),
                               0, stream, Yb, alpha, hbuf);
    }
    hipLaunchKernelGGL(k_head, dim3(BB * NFFT / 64), dim3(256), 0, stream,
                       hbuf, fc1_w, fc1_b, fc2_w, fc2_b, out);
}

// Round 4
// 155.880 us; speedup vs baseline: 2.1364x; 2.1364x over previous
//
#include <hip/hip_runtime.h>
#include <math.h>

#define NFFT   2048
#define LOG2N  11
#define BB     8
#define WW     32
#define MM     16
#define NLAYER 4

// Padded LDS index: +1 float per 32 -> breaks power-of-2 bank aliasing
#define PAD(i) ((i) + ((i) >> 5))
#define PADDED_N (NFFT + (NFFT >> 5))   // 2112

// ---------- fast gelu (exact-erf form, A&S 7.1.26, |err| <= 1.5e-7) ----------
__device__ __forceinline__ float gelu_f(float v) {
    float ax = fabsf(v) * 0.70710678118654752440f;
    float t  = __builtin_amdgcn_rcpf(fmaf(0.3275911f, ax, 1.0f));
    float s  = fmaf(1.061405429f, t, -1.453152027f);
    s = fmaf(s, t, 1.421413741f);
    s = fmaf(s, t, -0.284496736f);
    s = fmaf(s, t, 0.254829592f);
    s = s * t;
    float e  = __expf(-ax * ax);
    float er = fmaf(-s, e, 1.0f);          // erf(|v|/sqrt2)
    er = copysignf(er, v);
    return 0.5f * v * (1.0f + er);
}

// ---------- complex helpers ----------
__device__ __forceinline__ float2 cadd(float2 a, float2 b) { return make_float2(a.x + b.x, a.y + b.y); }
__device__ __forceinline__ float2 csub(float2 a, float2 b) { return make_float2(a.x - b.x, a.y - b.y); }
__device__ __forceinline__ float2 cmul(float2 a, float2 b) {
    return make_float2(fmaf(a.x, b.x, -a.y * b.y), fmaf(a.x, b.y, a.y * b.x));
}
// a + S*i*b  /  a - S*i*b   (S=-1 forward FFT, S=+1 inverse)
template<int S> __device__ __forceinline__ float2 caddi(float2 a, float2 b) {
    return (S > 0) ? make_float2(a.x - b.y, a.y + b.x) : make_float2(a.x + b.y, a.y - b.x);
}
template<int S> __device__ __forceinline__ float2 csubi(float2 a, float2 b) {
    return (S > 0) ? make_float2(a.x + b.y, a.y - b.x) : make_float2(a.x - b.y, a.y + b.x);
}

template<int S> __device__ __forceinline__ void dft4(float2* a) {
    float2 t0 = cadd(a[0], a[2]), t1 = csub(a[0], a[2]);
    float2 t2 = cadd(a[1], a[3]), t3 = csub(a[1], a[3]);
    a[0] = cadd(t0, t2);
    a[2] = csub(t0, t2);
    a[1] = caddi<S>(t1, t3);
    a[3] = csubi<S>(t1, t3);
}

template<int S> __device__ __forceinline__ void dft8(float2* a) {
    const float c = 0.70710678118654752440f;
    float2 t0 = cadd(a[0], a[4]), t1 = csub(a[0], a[4]);
    float2 t2 = cadd(a[2], a[6]), t3 = csub(a[2], a[6]);
    float2 u0 = cadd(a[1], a[5]), u1 = csub(a[1], a[5]);
    float2 u2 = cadd(a[3], a[7]), u3 = csub(a[3], a[7]);
    float2 e0 = cadd(t0, t2), e2 = csub(t0, t2);
    float2 e1 = caddi<S>(t1, t3), e3 = csubi<S>(t1, t3);
    float2 o0 = cadd(u0, u2), o2 = csub(u0, u2);
    float2 o1 = caddi<S>(u1, u3), o3 = csubi<S>(u1, u3);
    float2 w1o, w2o, w3o;
    if (S < 0) {  // forward: w1=c(1-i), w2=-i, w3=c(-1-i)
        w1o = make_float2(c * (o1.x + o1.y), c * (o1.y - o1.x));
        w2o = make_float2(o2.y, -o2.x);
        w3o = make_float2(c * (o3.y - o3.x), c * (-o3.y - o3.x));
    } else {      // inverse: conjugates
        w1o = make_float2(c * (o1.x - o1.y), c * (o1.y + o1.x));
        w2o = make_float2(-o2.y, o2.x);
        w3o = make_float2(c * (-o3.x - o3.y), c * (o3.x - o3.y));
    }
    a[0] = cadd(e0, o0);  a[4] = csub(e0, o0);
    a[1] = cadd(e1, w1o); a[5] = csub(e1, w1o);
    a[2] = cadd(e2, w2o); a[6] = csub(e2, w2o);
    a[3] = cadd(e3, w3o); a[7] = csub(e3, w3o);
}

// ---------- Stockham autosort passes (N=2048, 256 threads) ----------
template<int LS, int S>
__device__ __forceinline__ void pass_r8(const float* sre, const float* sim,
                                        float* dre, float* dim, int t) {
    const int s = t & (LS - 1);
    const int q = t / LS;
    float2 a[8];
    #pragma unroll
    for (int r = 0; r < 8; ++r) {
        int idx = t + r * 256;
        a[r] = make_float2(sre[PAD(idx)], sim[PAD(idx)]);
    }
    if (LS > 1) {
        float ph = (6.2831853071795864769f / (8.0f * (float)LS)) * (float)s;
        float sn, cs;
        __sincosf(ph, &sn, &cs);
        float2 w1 = make_float2(cs, (S > 0) ? sn : -sn);
        float2 wr = w1;
        a[1] = cmul(a[1], w1);
        #pragma unroll
        for (int r = 2; r < 8; ++r) { wr = cmul(wr, w1); a[r] = cmul(a[r], wr); }
    }
    dft8<S>(a);
    int base = q * (8 * LS) + s;
    #pragma unroll
    for (int r = 0; r < 8; ++r) {
        int idx = base + r * LS;
        dre[PAD(idx)] = a[r].x;
        dim[PAD(idx)] = a[r].y;
    }
}

template<int S>
__device__ __forceinline__ void pass_r4_512(const float* sre, const float* sim,
                                            float* dre, float* dim, int t) {
    #pragma unroll
    for (int h = 0; h < 2; ++h) {
        int j = t + h * 256;        // = s (q=0)
        float2 a[4];
        #pragma unroll
        for (int r = 0; r < 4; ++r) {
            int idx = j + r * 512;
            a[r] = make_float2(sre[PAD(idx)], sim[PAD(idx)]);
        }
        float ph = (6.2831853071795864769f / 2048.0f) * (float)j;
        float sn, cs;
        __sincosf(ph, &sn, &cs);
        float2 w1 = make_float2(cs, (S > 0) ? sn : -sn);
        a[1] = cmul(a[1], w1);
        float2 w2 = cmul(w1, w1);
        a[2] = cmul(a[2], w2);
        a[3] = cmul(a[3], cmul(w2, w1));
        dft4<S>(a);
        #pragma unroll
        for (int r = 0; r < 4; ++r) {
            int idx = r * 512 + j;
            dre[PAD(idx)] = a[r].x;
            dim[PAD(idx)] = a[r].y;
        }
    }
}

// In: natural order in A (padded). Out: natural order in A. Caller syncs before.
template<int S>
__device__ __forceinline__ void fft2048(float* Ar, float* Ai, float* Br, float* Bi, int t) {
    pass_r8<1, S>(Ar, Ai, Br, Bi, t);  __syncthreads();
    pass_r8<8, S>(Br, Bi, Ar, Ai, t);  __syncthreads();
    pass_r8<64, S>(Ar, Ai, Br, Bi, t); __syncthreads();
    pass_r4_512<S>(Br, Bi, Ar, Ai, t); __syncthreads();
}

// ---------- K0: h = gelu(fc0([x,grid])), forward FFT -> alpha ----------
__global__ __launch_bounds__(256) void k_fc0_fft(
    const float* __restrict__ x, const float* __restrict__ fc0_w,
    const float* __restrict__ fc0_b, float2* __restrict__ alpha)
{
    __shared__ float Ar[PADDED_N], Ai[PADDED_N], Br[PADDED_N], Bi[PADDED_N];
    int t = threadIdx.x;
    int row = blockIdx.x;            // b*32 + w
    int b = row >> 5, w = row & 31;
    float w0 = fc0_w[2 * w], w1 = fc0_w[2 * w + 1], b0 = fc0_b[w];
    #pragma unroll
    for (int j = 0; j < 8; ++j) {
        int idx = t + j * 256;
        float xv = x[b * NFFT + idx];
        float gv = (float)idx * (1.0f / 2047.0f);
        float val = gelu_f(fmaf(w0, xv, fmaf(w1, gv, b0)));
        Ar[PAD(idx)] = val;
        Ai[PAD(idx)] = 0.0f;
    }
    __syncthreads();
    fft2048<-1>(Ar, Ai, Br, Bi, t);
    #pragma unroll
    for (int j = 0; j < 8; ++j) {
        int k = t + j * 256;
        alpha[row * NFFT + k] = make_float2(Ar[PAD(k)], Ai[PAD(k)]);
    }
}

// ---------- K2: fused transfer function + channel einsum ----------
// H[i,o,k] = sum_m res/(lam_k - pole) + conv_w[o,i] + spec-fold(k)
// Y[b,o,k] = sum_i alpha[b,i,k]*H[i,o,k]  (+ L*conv_b[o] at k==0)
// 256 thr, 4 k/block, grid 512 -> 2 blocks/CU. No waves/EU constraint so the
// allocator keeps the ~50-reg mode-loop working set in VGPRs (round-3 lesson:
// forcing VGPR<=32 spilled 280 MB/dispatch to scratch).
__global__ __launch_bounds__(256) void k_apply(
    const float2* __restrict__ alpha, float2* __restrict__ Y,
    const float* __restrict__ pole_re, const float* __restrict__ pole_im,
    const float* __restrict__ res_re,  const float* __restrict__ res_im,
    const float* __restrict__ spec_re, const float* __restrict__ spec_im,
    const float* __restrict__ conv_w,  const float* __restrict__ conv_b,
    const float* __restrict__ tgrid, int layer)
{
    __shared__ float2 s_hw[WW][4][33];   // [o][kk][i], i padded  (33 KB)
    __shared__ float2 s_al[BB][WW][4];   // alpha tile [b][i][kk]  (8 KB)
    int t = threadIdx.x;
    int k0 = blockIdx.x * 4;
    float dt = tgrid[1] - tgrid[0];
    float fscale = 6.2831853071795864769f / ((float)NFFT * dt);
    float fk[4];
    #pragma unroll
    for (int kk = 0; kk < 4; ++kk) {
        int k = k0 + kk;
        int ks = (k < NFFT / 2) ? k : k - NFFT;
        fk[kk] = fscale * (float)ks;
    }

    // stage alpha tile: 1024 float2 slots, 4 per thread
    {
        int kl = t & 3, ii = (t >> 2) & 31, bq = t >> 7;   // bq 0..1
        #pragma unroll
        for (int j = 0; j < 4; ++j) {
            int b = bq + 2 * j;
            s_al[b][ii][kl] = alpha[(size_t)(b * WW + ii) * NFFT + k0 + kl];
        }
    }

    for (int pq = 0; pq < 4; ++pq) {             // 4 (i,o) pairs per thread
        int q = t + pq * 256;
        int i = q & 31, o = q >> 5;
        int pb = ((layer * WW + i) * WW + o) * MM;
        float cw = conv_w[(layer * WW + o) * WW + i];
        float2 acc[4];
        #pragma unroll
        for (int kk = 0; kk < 4; ++kk) acc[kk] = make_float2(cw, 0.0f);
        #pragma unroll
        for (int mq = 0; mq < 4; ++mq) {
            float4 P_re = *(const float4*)&pole_re[pb + 4 * mq];
            float4 P_im = *(const float4*)&pole_im[pb + 4 * mq];
            float4 R_re = *(const float4*)&res_re [pb + 4 * mq];
            float4 R_im = *(const float4*)&res_im [pb + 4 * mq];
            #pragma unroll
            for (int mm = 0; mm < 4; ++mm) {
                float pr = (&P_re.x)[mm], pi = (&P_im.x)[mm];
                float rr = (&R_re.x)[mm], ri = (&R_im.x)[mm];
                float c  = -pr;
                float c2 = c * c;
                float rc = rr * c;
                float ic = ri * c;
                #pragma unroll
                for (int kk = 0; kk < 4; ++kk) {
                    float d   = fk[kk] - pi;
                    float inv = __builtin_amdgcn_rcpf(fmaf(d, d, c2));
                    acc[kk].x = fmaf(fmaf(ri, d, rc), inv, acc[kk].x);
                    acc[kk].y = fmaf(fmaf(-rr, d, ic), inv, acc[kk].y);
                }
            }
        }
        if (k0 < MM || k0 >= NFFT - MM) {     // spectral fold (8 of 512 blocks)
            #pragma unroll
            for (int kk = 0; kk < 4; ++kk) {
                int k = k0 + kk;
                if (k < MM) {
                    acc[kk].x += spec_re[pb + k];
                    acc[kk].y += spec_im[pb + k];
                } else if (k > NFFT - MM) {   // conj bins (alpha Hermitian)
                    acc[kk].x += spec_re[pb + NFFT - k];
                    acc[kk].y -= spec_im[pb + NFFT - k];
                }
            }
        }
        #pragma unroll
        for (int kk = 0; kk < 4; ++kk) s_hw[o][kk][i] = acc[kk];
    }
    __syncthreads();

    // Phase 2: thread = (kl, o2, bq), 4 b's per thread; all reads from LDS.
    int kl = t & 3, o2 = (t >> 2) & 31, bq = t >> 7;
    int k = k0 + kl;
    float2 acc2[4];
    #pragma unroll
    for (int j = 0; j < 4; ++j) acc2[j] = make_float2(0.0f, 0.0f);
    #pragma unroll 8
    for (int ii = 0; ii < 32; ++ii) {
        float2 hh = s_hw[o2][kl][ii];
        #pragma unroll
        for (int j = 0; j < 4; ++j) {
            float2 av = s_al[bq + 2 * j][ii][kl];
            acc2[j].x = fmaf(av.x, hh.x, fmaf(-av.y, hh.y, acc2[j].x));
            acc2[j].y = fmaf(av.x, hh.y, fmaf( av.y, hh.x, acc2[j].y));
        }
    }
    if (k == 0) {
        float cb = (float)NFFT * conv_b[layer * WW + o2];
        #pragma unroll
        for (int j = 0; j < 4; ++j) acc2[j].x += cb;
    }
    #pragma unroll
    for (int j = 0; j < 4; ++j) {
        int b = bq + 2 * j;
        Y[(size_t)(b * WW + o2) * NFFT + k] = acc2[j];
    }
}

// ---------- K4: ifft -> Re/N -> gelu -> (forward fft | store h) ----------
template<bool LAST>
__global__ __launch_bounds__(256) void k_ifft_gelu_fft(
    const float2* __restrict__ Y, float2* __restrict__ alpha,
    float* __restrict__ hout)
{
    __shared__ float Ar[PADDED_N], Ai[PADDED_N], Br[PADDED_N], Bi[PADDED_N];
    int t = threadIdx.x;
    int row = blockIdx.x;
    #pragma unroll
    for (int j = 0; j < 8; ++j) {
        int k = t + j * 256;
        float2 v = Y[row * NFFT + k];
        Ar[PAD(k)] = v.x;
        Ai[PAD(k)] = v.y;
    }
    __syncthreads();
    fft2048<1>(Ar, Ai, Br, Bi, t);        // unnormalized inverse
    float vals[8];
    #pragma unroll
    for (int j = 0; j < 8; ++j) {
        int l = t + j * 256;
        vals[j] = gelu_f(Ar[PAD(l)] * (1.0f / (float)NFFT));
    }
    if (LAST) {
        #pragma unroll
        for (int j = 0; j < 8; ++j) hout[row * NFFT + t + j * 256] = vals[j];
    } else {
        __syncthreads();                  // all reads of Ar done
        #pragma unroll
        for (int j = 0; j < 8; ++j) {
            int idx = t + j * 256;
            Ar[PAD(idx)] = vals[j];
            Ai[PAD(idx)] = 0.0f;
        }
        __syncthreads();
        fft2048<-1>(Ar, Ai, Br, Bi, t);
        #pragma unroll
        for (int j = 0; j < 8; ++j) {
            int k = t + j * 256;
            alpha[row * NFFT + k] = make_float2(Ar[PAD(k)], Ai[PAD(k)]);
        }
    }
}

// ---------- K5: head. 4 waves/block, wave = n-group (uniform n -> LDS bcast) --
__global__ __launch_bounds__(256) void k_head(
    const float* __restrict__ h, const float* __restrict__ fc1_w,
    const float* __restrict__ fc1_b, const float* __restrict__ fc2_w,
    const float* __restrict__ fc2_b, float* __restrict__ out)
{
    __shared__ float s_w1[128 * 32];
    __shared__ float s_b1[128];
    __shared__ float s_w2[128];
    __shared__ float s_part[4][64];
    int t = threadIdx.x;
    for (int j = t; j < 128 * 32; j += 256) s_w1[j] = fc1_w[j];
    if (t < 128) { s_b1[t] = fc1_b[t]; s_w2[t] = fc2_w[t]; }
    __syncthreads();
    int wv  = t >> 6;                       // wave id = n-group
    int ln  = t & 63;
    int pos = blockIdx.x * 64 + ln;         // b*2048 + l
    int b = pos >> LOG2N, l = pos & (NFFT - 1);
    float hreg[32];
    #pragma unroll
    for (int w = 0; w < 32; ++w) hreg[w] = h[(b * WW + w) * NFFT + l];
    float acc = 0.0f;
    int n0 = wv * 32;
    for (int n = n0; n < n0 + 32; ++n) {
        float a = s_b1[n];
        #pragma unroll
        for (int w = 0; w < 32; w += 4) {
            float4 ww = *(const float4*)&s_w1[n * 32 + w];
            a = fmaf(ww.x, hreg[w],     a);
            a = fmaf(ww.y, hreg[w + 1], a);
            a = fmaf(ww.z, hreg[w + 2], a);
            a = fmaf(ww.w, hreg[w + 3], a);
        }
        acc = fmaf(s_w2[n], gelu_f(a), acc);
    }
    s_part[wv][ln] = acc;
    __syncthreads();
    if (t < 64) {
        float r = s_part[0][t] + s_part[1][t] + s_part[2][t] + s_part[3][t] + fc2_b[0];
        out[blockIdx.x * 64 + t] = r;
    }
}

extern "C" void kernel_launch(void* const* d_in, const int* in_sizes, int n_in,
                              void* d_out, int out_size, void* d_ws, size_t ws_size,
                              hipStream_t stream)
{
    const float* x       = (const float*)d_in[0];
    const float* tg      = (const float*)d_in[1];
    const float* fc0_w   = (const float*)d_in[2];
    const float* fc0_b   = (const float*)d_in[3];
    const float* pole_re = (const float*)d_in[4];
    const float* pole_im = (const float*)d_in[5];
    const float* res_re  = (const float*)d_in[6];
    const float* res_im  = (const float*)d_in[7];
    const float* spec_re = (const float*)d_in[8];
    const float* spec_im = (const float*)d_in[9];
    const float* conv_w  = (const float*)d_in[10];
    const float* conv_b  = (const float*)d_in[11];
    const float* fc1_w   = (const float*)d_in[12];
    const float* fc1_b   = (const float*)d_in[13];
    const float* fc2_w   = (const float*)d_in[14];
    const float* fc2_b   = (const float*)d_in[15];
    float* out = (float*)d_out;

    char* ws = (char*)d_ws;
    const size_t plane = (size_t)(BB * WW) * NFFT * sizeof(float2);  // 4 MiB
    float2* alpha = (float2*)ws;
    float2* Yb    = (float2*)(ws + plane);
    float*  hbuf  = (float*)(ws + 2 * plane);

    hipLaunchKernelGGL(k_fc0_fft, dim3(BB * WW), dim3(256), 0, stream,
                       x, fc0_w, fc0_b, alpha);
    for (int layer = 0; layer < NLAYER; ++layer) {
        hipLaunchKernelGGL(k_apply, dim3(NFFT / 4), dim3(256), 0, stream,
                           alpha, Yb, pole_re, pole_im, res_re, res_im,
                           spec_re, spec_im, conv_w, conv_b, tg, layer);
        if (layer < NLAYER - 1)
            hipLaunchKernelGGL((k_ifft_gelu_fft<false>), dim3(BB * WW), dim3(256),
                               0, stream, Yb, alpha, (float*)nullptr);
        else
            hipLaunchKernelGGL((k_ifft_gelu_fft<true>), dim3(BB * WW), dim3(256),
                               0, stream, Yb, alpha, hbuf);
    }
    hipLaunchKernelGGL(k_head, dim3(BB * NFFT / 64), dim3(256), 0, stream,
                       hbuf, fc1_w, fc1_b, fc2_w, fc2_b, out);
}

// Round 5
// 130.592 us; speedup vs baseline: 2.5501x; 1.1936x over previous
//
#include <hip/hip_runtime.h>
#include <math.h>

#define NFFT   2048
#define M2     1024
#define LOG2N  11
#define BB     8
#define WW     32
#define MM     16
#define NLAYER 4
#define AST    1032      // row stride (float2) for alpha / Yh half-spectra

// Padded LDS index for 1024-pt FFT arrays
#define PAD(i) ((i) + ((i) >> 5))
#define PADDED_M (M2 + (M2 >> 5))   // 1056

// ---------- fast gelu (exact-erf form, A&S 7.1.26, |err| <= 1.5e-7) ----------
__device__ __forceinline__ float gelu_f(float v) {
    float ax = fabsf(v) * 0.70710678118654752440f;
    float t  = __builtin_amdgcn_rcpf(fmaf(0.3275911f, ax, 1.0f));
    float s  = fmaf(1.061405429f, t, -1.453152027f);
    s = fmaf(s, t, 1.421413741f);
    s = fmaf(s, t, -0.284496736f);
    s = fmaf(s, t, 0.254829592f);
    s = s * t;
    float e  = __expf(-ax * ax);
    float er = fmaf(-s, e, 1.0f);          // erf(|v|/sqrt2)
    er = copysignf(er, v);
    return 0.5f * v * (1.0f + er);
}

// ---------- complex helpers ----------
__device__ __forceinline__ float2 cadd(float2 a, float2 b) { return make_float2(a.x + b.x, a.y + b.y); }
__device__ __forceinline__ float2 csub(float2 a, float2 b) { return make_float2(a.x - b.x, a.y - b.y); }
__device__ __forceinline__ float2 cmul(float2 a, float2 b) {
    return make_float2(fmaf(a.x, b.x, -a.y * b.y), fmaf(a.x, b.y, a.y * b.x));
}
template<int S> __device__ __forceinline__ float2 caddi(float2 a, float2 b) {
    return (S > 0) ? make_float2(a.x - b.y, a.y + b.x) : make_float2(a.x + b.y, a.y - b.x);
}
template<int S> __device__ __forceinline__ float2 csubi(float2 a, float2 b) {
    return (S > 0) ? make_float2(a.x + b.y, a.y - b.x) : make_float2(a.x - b.y, a.y + b.x);
}

template<int S> __device__ __forceinline__ void dft4(float2* a) {
    float2 t0 = cadd(a[0], a[2]), t1 = csub(a[0], a[2]);
    float2 t2 = cadd(a[1], a[3]), t3 = csub(a[1], a[3]);
    a[0] = cadd(t0, t2);
    a[2] = csub(t0, t2);
    a[1] = caddi<S>(t1, t3);
    a[3] = csubi<S>(t1, t3);
}

// ---------- Stockham radix-4 pass, N=1024, 256 threads, 1 butterfly/thread ---
template<int LS, int S>
__device__ __forceinline__ void pass_r4(const float* sre, const float* sim,
                                        float* dre, float* dim, int t) {
    const int s = t & (LS - 1);
    const int q = t / LS;
    float2 a[4];
    #pragma unroll
    for (int r = 0; r < 4; ++r) {
        int idx = t + r * 256;
        a[r] = make_float2(sre[PAD(idx)], sim[PAD(idx)]);
    }
    if (LS > 1) {
        float ph = (6.2831853071795864769f / (4.0f * (float)LS)) * (float)s;
        float sn, cs;
        __sincosf(ph, &sn, &cs);
        float2 w1 = make_float2(cs, (S > 0) ? sn : -sn);
        float2 w2 = cmul(w1, w1);
        a[1] = cmul(a[1], w1);
        a[2] = cmul(a[2], w2);
        a[3] = cmul(a[3], cmul(w2, w1));
    }
    dft4<S>(a);
    int base = q * (4 * LS) + s;
    #pragma unroll
    for (int r = 0; r < 4; ++r) {
        int idx = base + r * LS;
        dre[PAD(idx)] = a[r].x;
        dim[PAD(idx)] = a[r].y;
    }
}

// Input natural order in A; result lands in B. Caller syncs before call.
template<int S>
__device__ __forceinline__ void fft1024(float* Ar, float* Ai, float* Br, float* Bi, int t) {
    pass_r4<1,   S>(Ar, Ai, Br, Bi, t); __syncthreads();   // A -> B
    pass_r4<4,   S>(Br, Bi, Ar, Ai, t); __syncthreads();   // B -> A
    pass_r4<16,  S>(Ar, Ai, Br, Bi, t); __syncthreads();   // A -> B
    pass_r4<64,  S>(Br, Bi, Ar, Ai, t); __syncthreads();   // B -> A
    pass_r4<256, S>(Ar, Ai, Br, Bi, t); __syncthreads();   // A -> B (final)
}

// rfft unpack: Z (=fft1024 of packed z) in Br/Bi -> X[0..1024] to global row.
__device__ __forceinline__ void unpack_store(const float* Br, const float* Bi,
                                             float2* __restrict__ arow, int t) {
    #pragma unroll
    for (int j = 0; j < 4; ++j) {
        int k  = t + j * 256;
        int mk = (M2 - k) & (M2 - 1);
        float2 Zk  = make_float2(Br[PAD(k)],  Bi[PAD(k)]);
        float2 Zmk = make_float2(Br[PAD(mk)], Bi[PAD(mk)]);
        float2 A  = make_float2(0.5f * (Zk.x + Zmk.x), 0.5f * (Zk.y - Zmk.y));
        float2 Bv = make_float2(0.5f * (Zk.y + Zmk.y), -0.5f * (Zk.x - Zmk.x));
        float ph = (3.1415926535897932385f / (float)M2) * (float)k;
        float sn, cs;
        __sincosf(ph, &sn, &cs);
        float2 e = make_float2(cs, -sn);           // e^{-i*2pi*k/N}
        float2 X = cadd(A, cmul(Bv, e));
        arow[k] = X;
        if (k == 0)   // Nyquist bin: X[M] = A0 - B0 (both real)
            arow[M2] = make_float2(A.x - Bv.x, 0.0f);
    }
}

// ---------- K0: h = gelu(fc0([x,grid])), rfft -> alpha[0..1024] ----------
__global__ __launch_bounds__(256) void k_fc0_fft(
    const float* __restrict__ x, const float* __restrict__ fc0_w,
    const float* __restrict__ fc0_b, float2* __restrict__ alpha)
{
    __shared__ float Ar[PADDED_M], Ai[PADDED_M], Br[PADDED_M], Bi[PADDED_M];
    int t = threadIdx.x;
    int row = blockIdx.x;            // b*32 + w
    int b = row >> 5, w = row & 31;
    float w0 = fc0_w[2 * w], w1 = fc0_w[2 * w + 1], b0 = fc0_b[w];
    #pragma unroll
    for (int j = 0; j < 8; ++j) {
        int idx = t + j * 256;
        float xv = x[b * NFFT + idx];
        float gv = (float)idx * (1.0f / 2047.0f);
        float val = gelu_f(fmaf(w0, xv, fmaf(w1, gv, b0)));
        int n = idx >> 1;
        if (idx & 1) Ai[PAD(n)] = val;   // z[n] = h[2n] + i h[2n+1]
        else         Ar[PAD(n)] = val;
    }
    __syncthreads();
    fft1024<-1>(Ar, Ai, Br, Bi, t);
    unpack_store(Br, Bi, alpha + (size_t)row * AST, t);
}

// ---------- K2: half-spectrum transfer function + channel einsum ----------
// G[i,o,k] = sum_m (i*w*a - b)/((c-w^2) - i*d*w)   [pole-pair combined, real coefs]
//            + conv_w[o,i] + spec[k<16]    (k=0,1024: Re-only special cases)
// Yh[b,o,k] = sum_i alpha[b,i,k]*G[i,o,k]  (+ N*conv_b[o] at k==0)
__global__ __launch_bounds__(512) void k_apply(
    const float2* __restrict__ alpha, float2* __restrict__ Yh,
    const float* __restrict__ pole_re, const float* __restrict__ pole_im,
    const float* __restrict__ res_re,  const float* __restrict__ res_im,
    const float* __restrict__ spec_re, const float* __restrict__ spec_im,
    const float* __restrict__ conv_w,  const float* __restrict__ conv_b,
    const float* __restrict__ tgrid, int layer)
{
    __shared__ float2 s_hw[WW][4][35];   // [o][kk][i], i-dim 35 -> phase-2 reads conflict-free
    __shared__ float2 s_al[BB][WW][4];   // alpha tile [b][i][kk]
    int t = threadIdx.x;
    int k0 = blockIdx.x * 4;
    float dt = tgrid[1] - tgrid[0];
    float fscale = 6.2831853071795864769f / ((float)NFFT * dt);

    // stage alpha tile first: global loads overlap the long phase-1 ALU work
    {
        int kl = t & 3, ii = (t >> 2) & 31, bq = t >> 7;   // bq 0..3
        s_al[bq    ][ii][kl] = alpha[(size_t)((bq    ) * WW + ii) * AST + k0 + kl];
        s_al[bq + 4][ii][kl] = alpha[(size_t)((bq + 4) * WW + ii) * AST + k0 + kl];
    }

    if (k0 < M2) {               // normal bins: pole-pair combined formula
        float wv[4], w2[4];
        #pragma unroll
        for (int kk = 0; kk < 4; ++kk) {
            wv[kk] = fscale * (float)(k0 + kk);
            w2[kk] = wv[kk] * wv[kk];
        }
        #pragma unroll
        for (int p = 0; p < 2; ++p) {            // 2 (i,o) pairs per thread
            int q = t + p * 512;
            int i = q & 31, o = q >> 5;
            int pb = ((layer * WW + i) * WW + o) * MM;
            float cw = conv_w[(layer * WW + o) * WW + i];
            float2 acc[4];
            #pragma unroll
            for (int kk = 0; kk < 4; ++kk) acc[kk] = make_float2(cw, 0.0f);
            #pragma unroll
            for (int mq = 0; mq < 4; ++mq) {
                float4 P_re = *(const float4*)&pole_re[pb + 4 * mq];
                float4 P_im = *(const float4*)&pole_im[pb + 4 * mq];
                float4 R_re = *(const float4*)&res_re [pb + 4 * mq];
                float4 R_im = *(const float4*)&res_im [pb + 4 * mq];
                #pragma unroll
                for (int mm = 0; mm < 4; ++mm) {
                    float Rp = (&P_re.x)[mm], Ip = (&P_im.x)[mm];
                    float Rr = (&R_re.x)[mm], Ir = (&R_im.x)[mm];
                    float a   = Rr;
                    float b   = fmaf(Rr, Rp, Ir * Ip);      // Re(r * conj(p))
                    float c   = fmaf(Rp, Rp, Ip * Ip);      // |p|^2
                    float dd  = 2.0f * Rp;
                    float dd2 = dd * dd;
                    float add = a * dd;
                    float bdd = b * dd;
                    #pragma unroll
                    for (int kk = 0; kk < 4; ++kk) {
                        float u   = c - w2[kk];
                        float inv = __builtin_amdgcn_rcpf(fmaf(dd2, w2[kk], u * u));
                        float xn  = fmaf(add, w2[kk], b * u);
                        acc[kk].x = fmaf(xn, -inv, acc[kk].x);
                        float yn  = fmaf(a, u, -bdd) * inv;
                        acc[kk].y = fmaf(yn, wv[kk], acc[kk].y);
                    }
                }
            }
            if (k0 < MM) {           // spectral-conv fold (blocks 0..3 only)
                #pragma unroll
                for (int kk = 0; kk < 4; ++kk) {
                    int k = k0 + kk;
                    if (k) {
                        acc[kk].x += spec_re[pb + k];
                        acc[kk].y += spec_im[pb + k];
                    } else {         // DC must stay real
                        acc[kk].x += spec_re[pb];
                    }
                }
            }
            #pragma unroll
            for (int kk = 0; kk < 4; ++kk) s_hw[o][kk][i] = acc[kk];
        }
    } else {                     // Nyquist block: G = Re(H(w_nyq)), w negative
        float wn = -fscale * (float)M2;
        #pragma unroll
        for (int p = 0; p < 2; ++p) {
            int q = t + p * 512;
            int i = q & 31, o = q >> 5;
            int pb = ((layer * WW + i) * WW + o) * MM;
            float accx = conv_w[(layer * WW + o) * WW + i];
            #pragma unroll
            for (int mq = 0; mq < 4; ++mq) {
                float4 P_re = *(const float4*)&pole_re[pb + 4 * mq];
                float4 P_im = *(const float4*)&pole_im[pb + 4 * mq];
                float4 R_re = *(const float4*)&res_re [pb + 4 * mq];
                float4 R_im = *(const float4*)&res_im [pb + 4 * mq];
                #pragma unroll
                for (int mm = 0; mm < 4; ++mm) {
                    float Rp = (&P_re.x)[mm], Ip = (&P_im.x)[mm];
                    float Rr = (&R_re.x)[mm], Ir = (&R_im.x)[mm];
                    float e   = wn - Ip;
                    float num = fmaf(Ir, e, -(Rr * Rp));
                    float den = fmaf(e, e, Rp * Rp);
                    accx += num * __builtin_amdgcn_rcpf(den);
                }
            }
            s_hw[o][0][i] = make_float2(accx, 0.0f);
        }
    }
    __syncthreads();

    // Phase 2: thread = (kl, o2, bq); handles b = bq and bq+4. All LDS reads.
    int kl = t & 3, o2 = (t >> 2) & 31, bq = t >> 7;
    int k = k0 + kl;
    float2 acc0 = make_float2(0.0f, 0.0f);
    float2 acc1 = make_float2(0.0f, 0.0f);
    #pragma unroll 8
    for (int ii = 0; ii < 32; ++ii) {
        float2 hh = s_hw[o2][kl][ii];
        float2 a0 = s_al[bq][ii][kl];
        float2 a1 = s_al[bq + 4][ii][kl];
        acc0.x = fmaf(a0.x, hh.x, fmaf(-a0.y, hh.y, acc0.x));
        acc0.y = fmaf(a0.x, hh.y, fmaf( a0.y, hh.x, acc0.y));
        acc1.x = fmaf(a1.x, hh.x, fmaf(-a1.y, hh.y, acc1.x));
        acc1.y = fmaf(a1.x, hh.y, fmaf( a1.y, hh.x, acc1.y));
    }
    if (k == 0) {
        float cb = (float)NFFT * conv_b[layer * WW + o2];
        acc0.x += cb;
        acc1.x += cb;
    }
    if (k <= M2) {
        Yh[(size_t)(bq * WW + o2) * AST + k] = acc0;
        Yh[(size_t)((bq + 4) * WW + o2) * AST + k] = acc1;
    }
}

// ---------- K4: irfft(Yh) -> gelu -> (rfft -> alpha | store h) ----------
template<bool LAST>
__global__ __launch_bounds__(256) void k_irfft_gelu_rfft(
    const float2* __restrict__ Yh, float2* __restrict__ alpha,
    float2* __restrict__ hout)
{
    __shared__ float Ar[PADDED_M], Ai[PADDED_M], Br[PADDED_M], Bi[PADDED_M];
    int t = threadIdx.x;
    int row = blockIdx.x;
    const float2* yrow = Yh + (size_t)row * AST;
    // irfft pack: Z[k] = A + iB, B = e^{+i*2pi*k/N} * (X[k]-conj(X[M-k]))/2
    #pragma unroll
    for (int j = 0; j < 4; ++j) {
        int k = t + j * 256;
        float2 Xk = yrow[k];
        float2 Xm = yrow[M2 - k];
        float2 A = make_float2(0.5f * (Xk.x + Xm.x), 0.5f * (Xk.y - Xm.y));
        float2 u = make_float2(Xk.x - Xm.x, Xk.y + Xm.y);
        float ph = (3.1415926535897932385f / (float)M2) * (float)k;
        float sn, cs;
        __sincosf(ph, &sn, &cs);
        float2 e = make_float2(cs, sn);            // e^{+i*2pi*k/N}
        float2 Bv = cmul(u, e);
        Ar[PAD(k)] = A.x - 0.5f * Bv.y;
        Ai[PAD(k)] = A.y + 0.5f * Bv.x;
    }
    __syncthreads();
    fft1024<1>(Ar, Ai, Br, Bi, t);        // unnormalized inverse -> B
    // x[2n]=Re(z)/M, x[2n+1]=Im(z)/M ; gelu ; repack for forward rfft
    const float invM = 1.0f / (float)M2;
    if (LAST) {
        #pragma unroll
        for (int j = 0; j < 4; ++j) {
            int n = t + j * 256;
            float ge = gelu_f(Br[PAD(n)] * invM);
            float go = gelu_f(Bi[PAD(n)] * invM);
            hout[(size_t)row * M2 + n] = make_float2(ge, go);
        }
    } else {
        #pragma unroll
        for (int j = 0; j < 4; ++j) {
            int n = t + j * 256;
            float ge = gelu_f(Br[PAD(n)] * invM);
            float go = gelu_f(Bi[PAD(n)] * invM);
            Ar[PAD(n)] = ge;               // safe: pass-5 reads of A are done
            Ai[PAD(n)] = go;
        }
        __syncthreads();
        fft1024<-1>(Ar, Ai, Br, Bi, t);
        unpack_store(Br, Bi, alpha + (size_t)row * AST, t);
    }
}

// ---------- K5: head ----------
__global__ __launch_bounds__(256) void k_head(
    const float* __restrict__ h, const float* __restrict__ fc1_w,
    const float* __restrict__ fc1_b, const float* __restrict__ fc2_w,
    const float* __restrict__ fc2_b, float* __restrict__ out)
{
    __shared__ float s_w1[128 * 32];
    __shared__ float s_b1[128];
    __shared__ float s_w2[128];
    __shared__ float s_part[4][64];
    int t = threadIdx.x;
    for (int j = t; j < 128 * 32; j += 256) s_w1[j] = fc1_w[j];
    if (t < 128) { s_b1[t] = fc1_b[t]; s_w2[t] = fc2_w[t]; }
    __syncthreads();
    int wv  = t >> 6;                       // wave id = n-group
    int ln  = t & 63;
    int pos = blockIdx.x * 64 + ln;         // b*2048 + l
    int b = pos >> LOG2N, l = pos & (NFFT - 1);
    float hreg[32];
    #pragma unroll
    for (int w = 0; w < 32; ++w) hreg[w] = h[(b * WW + w) * NFFT + l];
    float acc = 0.0f;
    int n0 = wv * 32;
    for (int n = n0; n < n0 + 32; ++n) {
        float a = s_b1[n];
        #pragma unroll
        for (int w = 0; w < 32; w += 4) {
            float4 ww = *(const float4*)&s_w1[n * 32 + w];
            a = fmaf(ww.x, hreg[w],     a);
            a = fmaf(ww.y, hreg[w + 1], a);
            a = fmaf(ww.z, hreg[w + 2], a);
            a = fmaf(ww.w, hreg[w + 3], a);
        }
        acc = fmaf(s_w2[n], gelu_f(a), acc);
    }
    s_part[wv][ln] = acc;
    __syncthreads();
    if (t < 64) {
        float r = s_part[0][t] + s_part[1][t] + s_part[2][t] + s_part[3][t] + fc2_b[0];
        out[blockIdx.x * 64 + t] = r;
    }
}

extern "C" void kernel_launch(void* const* d_in, const int* in_sizes, int n_in,
                              void* d_out, int out_size, void* d_ws, size_t ws_size,
                              hipStream_t stream)
{
    const float* x       = (const float*)d_in[0];
    const float* tg      = (const float*)d_in[1];
    const float* fc0_w   = (const float*)d_in[2];
    const float* fc0_b   = (const float*)d_in[3];
    const float* pole_re = (const float*)d_in[4];
    const float* pole_im = (const float*)d_in[5];
    const float* res_re  = (const float*)d_in[6];
    const float* res_im  = (const float*)d_in[7];
    const float* spec_re = (const float*)d_in[8];
    const float* spec_im = (const float*)d_in[9];
    const float* conv_w  = (const float*)d_in[10];
    const float* conv_b  = (const float*)d_in[11];
    const float* fc1_w   = (const float*)d_in[12];
    const float* fc1_b   = (const float*)d_in[13];
    const float* fc2_w   = (const float*)d_in[14];
    const float* fc2_b   = (const float*)d_in[15];
    float* out = (float*)d_out;

    char* ws = (char*)d_ws;
    const size_t plane = (size_t)(BB * WW) * AST * sizeof(float2);  // 2.1 MiB
    float2* alpha = (float2*)ws;
    float2* Yb    = (float2*)(ws + plane);
    float2* hbuf  = (float2*)(ws + 2 * plane);

    hipLaunchKernelGGL(k_fc0_fft, dim3(BB * WW), dim3(256), 0, stream,
                       x, fc0_w, fc0_b, alpha);
    for (int layer = 0; layer < NLAYER; ++layer) {
        hipLaunchKernelGGL(k_apply, dim3(257), dim3(512), 0, stream,
                           alpha, Yb, pole_re, pole_im, res_re, res_im,
                           spec_re, spec_im, conv_w, conv_b, tg, layer);
        if (layer < NLAYER - 1)
            hipLaunchKernelGGL((k_irfft_gelu_rfft<false>), dim3(BB * WW), dim3(256),
                               0, stream, Yb, alpha, (float2*)nullptr);
        else
            hipLaunchKernelGGL((k_irfft_gelu_rfft<true>), dim3(BB * WW), dim3(256),
                               0, stream, Yb, alpha, hbuf);
    }
    hipLaunchKernelGGL(k_head, dim3(BB * NFFT / 64), dim3(256), 0, stream,
                       (const float*)hbuf, fc1_w, fc1_b, fc2_w, fc2_b, out);
}

// Round 6
// 122.027 us; speedup vs baseline: 2.7291x; 1.0702x over previous
//
#include <hip/hip_runtime.h>
#include <math.h>

#define NFFT   2048
#define M2     1024
#define LOG2N  11
#define BB     8
#define WW     32
#define MM     16
#define NLAYER 4
#define AST    1032      // row stride (float2) for alpha / G half-spectra

// Padded LDS index for 1024-pt FFT arrays
#define PAD(i) ((i) + ((i) >> 5))
#define PADDED_M (M2 + (M2 >> 5))   // 1056

// ---------- fast gelu (exact-erf form, A&S 7.1.26, |err| <= 1.5e-7) ----------
__device__ __forceinline__ float gelu_f(float v) {
    float ax = fabsf(v) * 0.70710678118654752440f;
    float t  = __builtin_amdgcn_rcpf(fmaf(0.3275911f, ax, 1.0f));
    float s  = fmaf(1.061405429f, t, -1.453152027f);
    s = fmaf(s, t, 1.421413741f);
    s = fmaf(s, t, -0.284496736f);
    s = fmaf(s, t, 0.254829592f);
    s = s * t;
    float e  = __expf(-ax * ax);
    float er = fmaf(-s, e, 1.0f);          // erf(|v|/sqrt2)
    er = copysignf(er, v);
    return 0.5f * v * (1.0f + er);
}

// ---------- complex helpers ----------
__device__ __forceinline__ float2 cadd(float2 a, float2 b) { return make_float2(a.x + b.x, a.y + b.y); }
__device__ __forceinline__ float2 csub(float2 a, float2 b) { return make_float2(a.x - b.x, a.y - b.y); }
__device__ __forceinline__ float2 cmul(float2 a, float2 b) {
    return make_float2(fmaf(a.x, b.x, -a.y * b.y), fmaf(a.x, b.y, a.y * b.x));
}
template<int S> __device__ __forceinline__ float2 caddi(float2 a, float2 b) {
    return (S > 0) ? make_float2(a.x - b.y, a.y + b.x) : make_float2(a.x + b.y, a.y - b.x);
}
template<int S> __device__ __forceinline__ float2 csubi(float2 a, float2 b) {
    return (S > 0) ? make_float2(a.x + b.y, a.y - b.x) : make_float2(a.x - b.y, a.y + b.x);
}

template<int S> __device__ __forceinline__ void dft4(float2* a) {
    float2 t0 = cadd(a[0], a[2]), t1 = csub(a[0], a[2]);
    float2 t2 = cadd(a[1], a[3]), t3 = csub(a[1], a[3]);
    a[0] = cadd(t0, t2);
    a[2] = csub(t0, t2);
    a[1] = caddi<S>(t1, t3);
    a[3] = csubi<S>(t1, t3);
}

// ---------- Stockham radix-4 pass, N=1024, 256 active threads ----------
template<int LS, int S>
__device__ __forceinline__ void pass_r4(const float* sre, const float* sim,
                                        float* dre, float* dim, int t) {
    const int s = t & (LS - 1);
    const int q = t / LS;
    float2 a[4];
    #pragma unroll
    for (int r = 0; r < 4; ++r) {
        int idx = t + r * 256;
        a[r] = make_float2(sre[PAD(idx)], sim[PAD(idx)]);
    }
    if (LS > 1) {
        float ph = (6.2831853071795864769f / (4.0f * (float)LS)) * (float)s;
        float sn, cs;
        __sincosf(ph, &sn, &cs);
        float2 w1 = make_float2(cs, (S > 0) ? sn : -sn);
        float2 w2 = cmul(w1, w1);
        a[1] = cmul(a[1], w1);
        a[2] = cmul(a[2], w2);
        a[3] = cmul(a[3], cmul(w2, w1));
    }
    dft4<S>(a);
    int base = q * (4 * LS) + s;
    #pragma unroll
    for (int r = 0; r < 4; ++r) {
        int idx = base + r * LS;
        dre[PAD(idx)] = a[r].x;
        dim[PAD(idx)] = a[r].y;
    }
}

// Input natural order in A; result in B. Caller syncs before. act = (t<256).
template<int S>
__device__ __forceinline__ void fft1024_g(float* Ar, float* Ai, float* Br, float* Bi,
                                          int t, bool act) {
    if (act) pass_r4<1,   S>(Ar, Ai, Br, Bi, t);
    __syncthreads();
    if (act) pass_r4<4,   S>(Br, Bi, Ar, Ai, t);
    __syncthreads();
    if (act) pass_r4<16,  S>(Ar, Ai, Br, Bi, t);
    __syncthreads();
    if (act) pass_r4<64,  S>(Br, Bi, Ar, Ai, t);
    __syncthreads();
    if (act) pass_r4<256, S>(Ar, Ai, Br, Bi, t);
    __syncthreads();
}

// ---------- K_genG: G[l,o,i,k] for all layers (b-independent) ----------
// G = conv_w[o,i] + sum_m (pole-pair combined, real coefs) + spec[k<16]
// block = (l, o, khalf): 4*32*2 = 256 blocks, 256 threads; thread: bins k1, k1+256
__global__ __launch_bounds__(256) void k_genG(
    const float* __restrict__ pole_re, const float* __restrict__ pole_im,
    const float* __restrict__ res_re,  const float* __restrict__ res_im,
    const float* __restrict__ spec_re, const float* __restrict__ spec_im,
    const float* __restrict__ conv_w,  const float* __restrict__ tgrid,
    float2* __restrict__ G)
{
    int t = threadIdx.x;
    int blk = blockIdx.x;
    int khalf = blk & 1, o = (blk >> 1) & 31, l = blk >> 6;
    float dt = tgrid[1] - tgrid[0];
    float fscale = 6.2831853071795864769f / ((float)NFFT * dt);
    int k1 = khalf * 512 + t;
    int k2 = k1 + 256;
    float wv1 = fscale * (float)k1, w21 = wv1 * wv1;
    float wv2 = fscale * (float)k2, w22 = wv2 * wv2;
    float wn  = -fscale * (float)M2;         // Nyquist (negative freq)

    for (int i = 0; i < 32; ++i) {
        int pb = ((l * WW + i) * WW + o) * MM;
        float cw = conv_w[(l * WW + o) * WW + i];
        float2 acc1 = make_float2(cw, 0.0f);
        float2 acc2 = make_float2(cw, 0.0f);
        float accn = cw;
        #pragma unroll
        for (int mq = 0; mq < 4; ++mq) {
            float4 P_re = *(const float4*)&pole_re[pb + 4 * mq];
            float4 P_im = *(const float4*)&pole_im[pb + 4 * mq];
            float4 R_re = *(const float4*)&res_re [pb + 4 * mq];
            float4 R_im = *(const float4*)&res_im [pb + 4 * mq];
            #pragma unroll
            for (int mm = 0; mm < 4; ++mm) {
                float Rp = (&P_re.x)[mm], Ip = (&P_im.x)[mm];
                float Rr = (&R_re.x)[mm], Ir = (&R_im.x)[mm];
                float a   = Rr;
                float b   = fmaf(Rr, Rp, Ir * Ip);      // Re(r * conj(p))
                float c   = fmaf(Rp, Rp, Ip * Ip);      // |p|^2
                float dd  = 2.0f * Rp;
                float dd2 = dd * dd;
                float add = a * dd;
                float bdd = b * dd;
                {   // bin k1
                    float u   = c - w21;
                    float inv = __builtin_amdgcn_rcpf(fmaf(dd2, w21, u * u));
                    acc1.x = fmaf(fmaf(add, w21, b * u), -inv, acc1.x);
                    acc1.y = fmaf(fmaf(a, u, -bdd) * inv, wv1, acc1.y);
                }
                {   // bin k2
                    float u   = c - w22;
                    float inv = __builtin_amdgcn_rcpf(fmaf(dd2, w22, u * u));
                    acc2.x = fmaf(fmaf(add, w22, b * u), -inv, acc2.x);
                    acc2.y = fmaf(fmaf(a, u, -bdd) * inv, wv2, acc2.y);
                }
                if (khalf == 1 && t == 0) {   // Nyquist: Re(H(wn)) only
                    float e   = wn - Ip;
                    float num = fmaf(Ir, e, -(Rr * Rp));
                    float den = fmaf(e, e, Rp * Rp);
                    accn += num * __builtin_amdgcn_rcpf(den);
                }
            }
        }
        if (k1 < MM) {                 // spectral-conv fold (khalf=0, t<16)
            if (k1) {
                acc1.x += spec_re[pb + k1];
                acc1.y += spec_im[pb + k1];
            } else {
                acc1.x += spec_re[pb];     // DC stays real
            }
        }
        float2* grow = G + (size_t)((l * WW + o) * WW + i) * AST;
        grow[k1] = acc1;
        grow[k2] = acc2;
        if (khalf == 1 && t == 0) grow[M2] = make_float2(accn, 0.0f);
    }
}

// rfft unpack for 512 threads: Z in Br/Bi -> X[0..1024] to global row.
__device__ __forceinline__ void unpack_store512(const float* Br, const float* Bi,
                                                float2* __restrict__ arow, int t) {
    #pragma unroll
    for (int j = 0; j < 2; ++j) {
        int k  = t + j * 512;
        int mk = (M2 - k) & (M2 - 1);
        float2 Zk  = make_float2(Br[PAD(k)],  Bi[PAD(k)]);
        float2 Zmk = make_float2(Br[PAD(mk)], Bi[PAD(mk)]);
        float2 A  = make_float2(0.5f * (Zk.x + Zmk.x), 0.5f * (Zk.y - Zmk.y));
        float2 Bv = make_float2(0.5f * (Zk.y + Zmk.y), -0.5f * (Zk.x - Zmk.x));
        float ph = (3.1415926535897932385f / (float)M2) * (float)k;
        float sn, cs;
        __sincosf(ph, &sn, &cs);
        float2 e = make_float2(cs, -sn);           // e^{-i*2pi*k/N}
        float2 X = cadd(A, cmul(Bv, e));
        arow[k] = X;
        if (k == 0)   // Nyquist bin: real
            arow[M2] = make_float2(A.x - Bv.x, 0.0f);
    }
}

// ---------- K0: h = gelu(fc0([x,grid])), rfft -> alpha[0..1024] ----------
__global__ __launch_bounds__(256) void k_fc0_fft(
    const float* __restrict__ x, const float* __restrict__ fc0_w,
    const float* __restrict__ fc0_b, float2* __restrict__ alpha)
{
    __shared__ float Ar[PADDED_M], Ai[PADDED_M], Br[PADDED_M], Bi[PADDED_M];
    int t = threadIdx.x;
    int row = blockIdx.x;            // b*32 + w
    int b = row >> 5, w = row & 31;
    float w0 = fc0_w[2 * w], w1 = fc0_w[2 * w + 1], b0 = fc0_b[w];
    #pragma unroll
    for (int j = 0; j < 8; ++j) {
        int idx = t + j * 256;
        float xv = x[b * NFFT + idx];
        float gv = (float)idx * (1.0f / 2047.0f);
        float val = gelu_f(fmaf(w0, xv, fmaf(w1, gv, b0)));
        int n = idx >> 1;
        if (idx & 1) Ai[PAD(n)] = val;   // z[n] = h[2n] + i h[2n+1]
        else         Ar[PAD(n)] = val;
    }
    __syncthreads();
    fft1024_g<-1>(Ar, Ai, Br, Bi, t, true);
    // 256-thread unpack (4 bins each)
    #pragma unroll
    for (int j = 0; j < 4; ++j) {
        int k  = t + j * 256;
        int mk = (M2 - k) & (M2 - 1);
        float2 Zk  = make_float2(Br[PAD(k)],  Bi[PAD(k)]);
        float2 Zmk = make_float2(Br[PAD(mk)], Bi[PAD(mk)]);
        float2 A  = make_float2(0.5f * (Zk.x + Zmk.x), 0.5f * (Zk.y - Zmk.y));
        float2 Bv = make_float2(0.5f * (Zk.y + Zmk.y), -0.5f * (Zk.x - Zmk.x));
        float ph = (3.1415926535897932385f / (float)M2) * (float)k;
        float sn, cs;
        __sincosf(ph, &sn, &cs);
        float2 e = make_float2(cs, -sn);
        float2 X = cadd(A, cmul(Bv, e));
        float2* arow = alpha + (size_t)row * AST;
        arow[k] = X;
        if (k == 0) arow[M2] = make_float2(A.x - Bv.x, 0.0f);
    }
}

// ---------- K_layer: einsum over i + irfft + gelu + (rfft | store h) ----------
// block = (b,o) row, 512 threads. Yh[k] = sum_i alpha[b,i,k]*G[l,o,i,k]
template<bool LAST>
__global__ __launch_bounds__(512) void k_apply_fft(
    const float2* __restrict__ alpha, const float2* __restrict__ G,
    const float* __restrict__ conv_b, float2* __restrict__ alpha_next,
    float2* __restrict__ hout, int layer)
{
    __shared__ float Yr[M2 + 2], Yi[M2 + 2];
    __shared__ float Ar[PADDED_M], Ai[PADDED_M], Br[PADDED_M], Bi[PADDED_M];
    int t = threadIdx.x;
    int row = blockIdx.x;            // b*32 + o
    int b = row >> 5, o = row & 31;
    const float2* abase = alpha + (size_t)(b * WW) * AST;
    const float2* gbase = G + (size_t)((layer * WW + o) * WW) * AST;

    float2 acc0 = make_float2(0.0f, 0.0f);
    float2 acc1 = make_float2(0.0f, 0.0f);
    #pragma unroll 4
    for (int i = 0; i < 32; ++i) {
        float2 a0 = abase[(size_t)i * AST + t];
        float2 g0 = gbase[(size_t)i * AST + t];
        float2 a1 = abase[(size_t)i * AST + t + 512];
        float2 g1 = gbase[(size_t)i * AST + t + 512];
        acc0.x = fmaf(a0.x, g0.x, fmaf(-a0.y, g0.y, acc0.x));
        acc0.y = fmaf(a0.x, g0.y, fmaf( a0.y, g0.x, acc0.y));
        acc1.x = fmaf(a1.x, g1.x, fmaf(-a1.y, g1.y, acc1.x));
        acc1.y = fmaf(a1.x, g1.y, fmaf( a1.y, g1.x, acc1.y));
    }
    // Nyquist: real dot over i, wave-0 shuffle reduce
    if (t < 64) {
        float p = 0.0f;
        if (t < 32)
            p = abase[(size_t)t * AST + M2].x * gbase[(size_t)t * AST + M2].x;
        #pragma unroll
        for (int off = 16; off >= 1; off >>= 1) p += __shfl_xor(p, off);
        if (t == 0) { Yr[M2] = p; Yi[M2] = 0.0f; }
    }
    if (t == 0) acc0.x += (float)NFFT * conv_b[layer * WW + o];
    Yr[t] = acc0.x;        Yi[t] = acc0.y;
    Yr[t + 512] = acc1.x;  Yi[t + 512] = acc1.y;
    __syncthreads();

    // irfft pack: Z[k] = A + iB from X[k], X[M2-k]
    #pragma unroll
    for (int j = 0; j < 2; ++j) {
        int k = t + j * 512;
        float2 Xk = make_float2(Yr[k], Yi[k]);
        float2 Xm = make_float2(Yr[M2 - k], Yi[M2 - k]);
        float2 A = make_float2(0.5f * (Xk.x + Xm.x), 0.5f * (Xk.y - Xm.y));
        float2 u = make_float2(Xk.x - Xm.x, Xk.y + Xm.y);
        float ph = (3.1415926535897932385f / (float)M2) * (float)k;
        float sn, cs;
        __sincosf(ph, &sn, &cs);
        float2 e = make_float2(cs, sn);            // e^{+i*2pi*k/N}
        float2 Bv = cmul(u, e);
        Ar[PAD(k)] = A.x - 0.5f * Bv.y;
        Ai[PAD(k)] = A.y + 0.5f * Bv.x;
    }
    __syncthreads();
    fft1024_g<1>(Ar, Ai, Br, Bi, t, t < 256);     // inverse -> B
    const float invM = 1.0f / (float)M2;
    if (LAST) {
        #pragma unroll
        for (int j = 0; j < 2; ++j) {
            int n = t + j * 512;
            float ge = gelu_f(Br[PAD(n)] * invM);
            float go = gelu_f(Bi[PAD(n)] * invM);
            hout[(size_t)row * M2 + n] = make_float2(ge, go);
        }
    } else {
        #pragma unroll
        for (int j = 0; j < 2; ++j) {
            int n = t + j * 512;
            float ge = gelu_f(Br[PAD(n)] * invM);
            float go = gelu_f(Bi[PAD(n)] * invM);
            Ar[PAD(n)] = ge;
            Ai[PAD(n)] = go;
        }
        __syncthreads();
        fft1024_g<-1>(Ar, Ai, Br, Bi, t, t < 256);
        unpack_store512(Br, Bi, alpha_next + (size_t)row * AST, t);
    }
}

// ---------- K5: head ----------
__global__ __launch_bounds__(256) void k_head(
    const float* __restrict__ h, const float* __restrict__ fc1_w,
    const float* __restrict__ fc1_b, const float* __restrict__ fc2_w,
    const float* __restrict__ fc2_b, float* __restrict__ out)
{
    __shared__ float s_w1[128 * 32];
    __shared__ float s_b1[128];
    __shared__ float s_w2[128];
    __shared__ float s_part[4][64];
    int t = threadIdx.x;
    for (int j = t; j < 128 * 32; j += 256) s_w1[j] = fc1_w[j];
    if (t < 128) { s_b1[t] = fc1_b[t]; s_w2[t] = fc2_w[t]; }
    __syncthreads();
    int wv  = t >> 6;                       // wave id = n-group
    int ln  = t & 63;
    int pos = blockIdx.x * 64 + ln;         // b*2048 + l
    int b = pos >> LOG2N, l = pos & (NFFT - 1);
    float hreg[32];
    #pragma unroll
    for (int w = 0; w < 32; ++w) hreg[w] = h[(b * WW + w) * NFFT + l];
    float acc = 0.0f;
    int n0 = wv * 32;
    for (int n = n0; n < n0 + 32; ++n) {
        float a = s_b1[n];
        #pragma unroll
        for (int w = 0; w < 32; w += 4) {
            float4 ww = *(const float4*)&s_w1[n * 32 + w];
            a = fmaf(ww.x, hreg[w],     a);
            a = fmaf(ww.y, hreg[w + 1], a);
            a = fmaf(ww.z, hreg[w + 2], a);
            a = fmaf(ww.w, hreg[w + 3], a);
        }
        acc = fmaf(s_w2[n], gelu_f(a), acc);
    }
    s_part[wv][ln] = acc;
    __syncthreads();
    if (t < 64) {
        float r = s_part[0][t] + s_part[1][t] + s_part[2][t] + s_part[3][t] + fc2_b[0];
        out[blockIdx.x * 64 + t] = r;
    }
}

extern "C" void kernel_launch(void* const* d_in, const int* in_sizes, int n_in,
                              void* d_out, int out_size, void* d_ws, size_t ws_size,
                              hipStream_t stream)
{
    const float* x       = (const float*)d_in[0];
    const float* tg      = (const float*)d_in[1];
    const float* fc0_w   = (const float*)d_in[2];
    const float* fc0_b   = (const float*)d_in[3];
    const float* pole_re = (const float*)d_in[4];
    const float* pole_im = (const float*)d_in[5];
    const float* res_re  = (const float*)d_in[6];
    const float* res_im  = (const float*)d_in[7];
    const float* spec_re = (const float*)d_in[8];
    const float* spec_im = (const float*)d_in[9];
    const float* conv_w  = (const float*)d_in[10];
    const float* conv_b  = (const float*)d_in[11];
    const float* fc1_w   = (const float*)d_in[12];
    const float* fc1_b   = (const float*)d_in[13];
    const float* fc2_w   = (const float*)d_in[14];
    const float* fc2_b   = (const float*)d_in[15];
    float* out = (float*)d_out;

    char* ws = (char*)d_ws;
    const size_t plane = (size_t)(BB * WW) * AST * sizeof(float2);   // 2.11 MiB
    float2* alphaA = (float2*)ws;
    float2* alphaB = (float2*)(ws + plane);
    float2* hbuf   = (float2*)(ws + 2 * plane);                      // 2 MiB
    float2* Gbuf   = (float2*)(ws + 3 * plane + (size_t)(BB * WW) * M2 * sizeof(float2));

    hipLaunchKernelGGL(k_genG, dim3(256), dim3(256), 0, stream,
                       pole_re, pole_im, res_re, res_im,
                       spec_re, spec_im, conv_w, tg, Gbuf);
    hipLaunchKernelGGL(k_fc0_fft, dim3(BB * WW), dim3(256), 0, stream,
                       x, fc0_w, fc0_b, alphaA);
    float2* acur = alphaA;
    float2* anxt = alphaB;
    for (int layer = 0; layer < NLAYER; ++layer) {
        if (layer < NLAYER - 1)
            hipLaunchKernelGGL((k_apply_fft<false>), dim3(BB * WW), dim3(512), 0, stream,
                               acur, Gbuf, conv_b, anxt, (float2*)nullptr, layer);
        else
            hipLaunchKernelGGL((k_apply_fft<true>), dim3(BB * WW), dim3(512), 0, stream,
                               acur, Gbuf, conv_b, (float2*)nullptr, hbuf, layer);
        float2* tmp = acur; acur = anxt; anxt = tmp;
    }
    hipLaunchKernelGGL(k_head, dim3(BB * NFFT / 64), dim3(256), 0, stream,
                       (const float*)hbuf, fc1_w, fc1_b, fc2_w, fc2_b, out);
}

// Round 7
// 103.885 us; speedup vs baseline: 3.2057x; 1.1746x over previous
//
#include <hip/hip_runtime.h>
#include <math.h>

#define NFFT   2048
#define M2     1024
#define LOG2N  11
#define BB     8
#define WW     32
#define MM     16
#define NLAYER 4
#define AST    1032      // row stride (float2) for alpha / G half-spectra

// Padded LDS index for 1024-pt FFT arrays
#define PAD(i) ((i) + ((i) >> 5))
#define PADDED_M (M2 + (M2 >> 5))   // 1056

// ---------- fast gelu (exact-erf form, A&S 7.1.26, |err| <= 1.5e-7) ----------
__device__ __forceinline__ float gelu_f(float v) {
    float ax = fabsf(v) * 0.70710678118654752440f;
    float t  = __builtin_amdgcn_rcpf(fmaf(0.3275911f, ax, 1.0f));
    float s  = fmaf(1.061405429f, t, -1.453152027f);
    s = fmaf(s, t, 1.421413741f);
    s = fmaf(s, t, -0.284496736f);
    s = fmaf(s, t, 0.254829592f);
    s = s * t;
    float e  = __expf(-ax * ax);
    float er = fmaf(-s, e, 1.0f);          // erf(|v|/sqrt2)
    er = copysignf(er, v);
    return 0.5f * v * (1.0f + er);
}

// ---------- complex helpers ----------
__device__ __forceinline__ float2 cadd(float2 a, float2 b) { return make_float2(a.x + b.x, a.y + b.y); }
__device__ __forceinline__ float2 csub(float2 a, float2 b) { return make_float2(a.x - b.x, a.y - b.y); }
__device__ __forceinline__ float2 cmul(float2 a, float2 b) {
    return make_float2(fmaf(a.x, b.x, -a.y * b.y), fmaf(a.x, b.y, a.y * b.x));
}
template<int S> __device__ __forceinline__ float2 caddi(float2 a, float2 b) {
    return (S > 0) ? make_float2(a.x - b.y, a.y + b.x) : make_float2(a.x + b.y, a.y - b.x);
}
template<int S> __device__ __forceinline__ float2 csubi(float2 a, float2 b) {
    return (S > 0) ? make_float2(a.x + b.y, a.y - b.x) : make_float2(a.x - b.y, a.y + b.x);
}

template<int S> __device__ __forceinline__ void dft4(float2* a) {
    float2 t0 = cadd(a[0], a[2]), t1 = csub(a[0], a[2]);
    float2 t2 = cadd(a[1], a[3]), t3 = csub(a[1], a[3]);
    a[0] = cadd(t0, t2);
    a[2] = csub(t0, t2);
    a[1] = caddi<S>(t1, t3);
    a[3] = csubi<S>(t1, t3);
}

// ---------- Stockham radix-4 pass, N=1024, 256 active threads ----------
template<int LS, int S>
__device__ __forceinline__ void pass_r4(const float* sre, const float* sim,
                                        float* dre, float* dim, int t) {
    const int s = t & (LS - 1);
    const int q = t / LS;
    float2 a[4];
    #pragma unroll
    for (int r = 0; r < 4; ++r) {
        int idx = t + r * 256;
        a[r] = make_float2(sre[PAD(idx)], sim[PAD(idx)]);
    }
    if (LS > 1) {
        float ph = (6.2831853071795864769f / (4.0f * (float)LS)) * (float)s;
        float sn, cs;
        __sincosf(ph, &sn, &cs);
        float2 w1 = make_float2(cs, (S > 0) ? sn : -sn);
        float2 w2 = cmul(w1, w1);
        a[1] = cmul(a[1], w1);
        a[2] = cmul(a[2], w2);
        a[3] = cmul(a[3], cmul(w2, w1));
    }
    dft4<S>(a);
    int base = q * (4 * LS) + s;
    #pragma unroll
    for (int r = 0; r < 4; ++r) {
        int idx = base + r * LS;
        dre[PAD(idx)] = a[r].x;
        dim[PAD(idx)] = a[r].y;
    }
}

// Input natural order in A; result in B. Caller syncs before. act = (t<256).
template<int S>
__device__ __forceinline__ void fft1024_g(float* Ar, float* Ai, float* Br, float* Bi,
                                          int t, bool act) {
    if (act) pass_r4<1,   S>(Ar, Ai, Br, Bi, t);
    __syncthreads();
    if (act) pass_r4<4,   S>(Br, Bi, Ar, Ai, t);
    __syncthreads();
    if (act) pass_r4<16,  S>(Ar, Ai, Br, Bi, t);
    __syncthreads();
    if (act) pass_r4<64,  S>(Br, Bi, Ar, Ai, t);
    __syncthreads();
    if (act) pass_r4<256, S>(Ar, Ai, Br, Bi, t);
    __syncthreads();
}

// ---------- K_genG_fc0: fused G-generation (blocks 0..4095) + fc0+rfft ------
// genG block = one (l,o,i): 256 threads x 4 bins each. Params wave-uniform,
// loaded once; modes outer, bins inner. Wave 0 redoes Nyquist (cheap, hot K$).
__global__ __launch_bounds__(256) void k_genG_fc0(
    const float* __restrict__ pole_re, const float* __restrict__ pole_im,
    const float* __restrict__ res_re,  const float* __restrict__ res_im,
    const float* __restrict__ spec_re, const float* __restrict__ spec_im,
    const float* __restrict__ conv_w,  const float* __restrict__ tgrid,
    const float* __restrict__ x,       const float* __restrict__ fc0_w,
    const float* __restrict__ fc0_b,
    float2* __restrict__ G, float2* __restrict__ alpha)
{
    __shared__ float Ar[PADDED_M], Ai[PADDED_M], Br[PADDED_M], Bi[PADDED_M];
    int t = threadIdx.x;
    int blk = blockIdx.x;
    float dt = tgrid[1] - tgrid[0];
    float fscale = 6.2831853071795864769f / ((float)NFFT * dt);

    if (blk < NLAYER * WW * WW) {
        // ---- genG path ----
        int l = blk >> 10, r = blk & 1023, o = r >> 5, i = r & 31;
        int pb = ((l * WW + i) * WW + o) * MM;
        float cw = conv_w[(l * WW + o) * WW + i];
        float wv[4], w2[4];
        float2 acc[4];
        #pragma unroll
        for (int kk = 0; kk < 4; ++kk) {
            wv[kk] = fscale * (float)(t + kk * 256);
            w2[kk] = wv[kk] * wv[kk];
            acc[kk] = make_float2(cw, 0.0f);
        }
        #pragma unroll
        for (int mq = 0; mq < 4; ++mq) {
            float4 P_re = *(const float4*)&pole_re[pb + 4 * mq];
            float4 P_im = *(const float4*)&pole_im[pb + 4 * mq];
            float4 R_re = *(const float4*)&res_re [pb + 4 * mq];
            float4 R_im = *(const float4*)&res_im [pb + 4 * mq];
            #pragma unroll
            for (int mm = 0; mm < 4; ++mm) {
                float Rp = (&P_re.x)[mm], Ip = (&P_im.x)[mm];
                float Rr = (&R_re.x)[mm], Ir = (&R_im.x)[mm];
                float b   = fmaf(Rr, Rp, Ir * Ip);      // Re(r * conj(p))
                float c   = fmaf(Rp, Rp, Ip * Ip);      // |p|^2
                float dd  = 2.0f * Rp;
                float dd2 = dd * dd;
                float add = Rr * dd;
                float bdd = b * dd;
                #pragma unroll
                for (int kk = 0; kk < 4; ++kk) {
                    float u   = c - w2[kk];
                    float inv = __builtin_amdgcn_rcpf(fmaf(dd2, w2[kk], u * u));
                    acc[kk].x = fmaf(fmaf(add, w2[kk], b * u), -inv, acc[kk].x);
                    acc[kk].y = fmaf(fmaf(Rr, u, -bdd) * inv, wv[kk], acc[kk].y);
                }
            }
        }
        if (t < MM) {                  // spectral-conv fold: bins k=t<16 (kk=0)
            if (t) {
                acc[0].x += spec_re[pb + t];
                acc[0].y += spec_im[pb + t];
            } else {
                acc[0].x += spec_re[pb];     // DC stays real
            }
        }
        float2* grow = G + (size_t)((l * WW + o) * WW + i) * AST;
        #pragma unroll
        for (int kk = 0; kk < 4; ++kk) grow[t + kk * 256] = acc[kk];
        if (t < 64) {                  // Nyquist: wave 0 only, params hot
            float wn = -fscale * (float)M2;
            float accn = cw;
            #pragma unroll
            for (int mq = 0; mq < 4; ++mq) {
                float4 P_re = *(const float4*)&pole_re[pb + 4 * mq];
                float4 P_im = *(const float4*)&pole_im[pb + 4 * mq];
                float4 R_re = *(const float4*)&res_re [pb + 4 * mq];
                float4 R_im = *(const float4*)&res_im [pb + 4 * mq];
                #pragma unroll
                for (int mm = 0; mm < 4; ++mm) {
                    float Rp = (&P_re.x)[mm], Ip = (&P_im.x)[mm];
                    float Rr = (&R_re.x)[mm], Ir = (&R_im.x)[mm];
                    float e   = wn - Ip;
                    float num = fmaf(Ir, e, -(Rr * Rp));
                    float den = fmaf(e, e, Rp * Rp);
                    accn += num * __builtin_amdgcn_rcpf(den);
                }
            }
            if (t == 0) grow[M2] = make_float2(accn, 0.0f);
        }
    } else {
        // ---- fc0 + rfft path ----
        int row = blk - NLAYER * WW * WW;   // b*32 + w
        int b = row >> 5, w = row & 31;
        float w0 = fc0_w[2 * w], w1 = fc0_w[2 * w + 1], b0 = fc0_b[w];
        #pragma unroll
        for (int j = 0; j < 8; ++j) {
            int idx = t + j * 256;
            float xv = x[b * NFFT + idx];
            float gv = (float)idx * (1.0f / 2047.0f);
            float val = gelu_f(fmaf(w0, xv, fmaf(w1, gv, b0)));
            int n = idx >> 1;
            if (idx & 1) Ai[PAD(n)] = val;   // z[n] = h[2n] + i h[2n+1]
            else         Ar[PAD(n)] = val;
        }
        __syncthreads();
        fft1024_g<-1>(Ar, Ai, Br, Bi, t, true);
        #pragma unroll
        for (int j = 0; j < 4; ++j) {
            int k  = t + j * 256;
            int mk = (M2 - k) & (M2 - 1);
            float2 Zk  = make_float2(Br[PAD(k)],  Bi[PAD(k)]);
            float2 Zmk = make_float2(Br[PAD(mk)], Bi[PAD(mk)]);
            float2 A  = make_float2(0.5f * (Zk.x + Zmk.x), 0.5f * (Zk.y - Zmk.y));
            float2 Bv = make_float2(0.5f * (Zk.y + Zmk.y), -0.5f * (Zk.x - Zmk.x));
            float ph = (3.1415926535897932385f / (float)M2) * (float)k;
            float sn, cs;
            __sincosf(ph, &sn, &cs);
            float2 e = make_float2(cs, -sn);
            float2 X = cadd(A, cmul(Bv, e));
            float2* arow = alpha + (size_t)row * AST;
            arow[k] = X;
            if (k == 0) arow[M2] = make_float2(A.x - Bv.x, 0.0f);
        }
    }
}

// rfft unpack for 512 threads: Z in Br/Bi -> X[0..1024] to global row.
__device__ __forceinline__ void unpack_store512(const float* Br, const float* Bi,
                                                float2* __restrict__ arow, int t) {
    #pragma unroll
    for (int j = 0; j < 2; ++j) {
        int k  = t + j * 512;
        int mk = (M2 - k) & (M2 - 1);
        float2 Zk  = make_float2(Br[PAD(k)],  Bi[PAD(k)]);
        float2 Zmk = make_float2(Br[PAD(mk)], Bi[PAD(mk)]);
        float2 A  = make_float2(0.5f * (Zk.x + Zmk.x), 0.5f * (Zk.y - Zmk.y));
        float2 Bv = make_float2(0.5f * (Zk.y + Zmk.y), -0.5f * (Zk.x - Zmk.x));
        float ph = (3.1415926535897932385f / (float)M2) * (float)k;
        float sn, cs;
        __sincosf(ph, &sn, &cs);
        float2 e = make_float2(cs, -sn);           // e^{-i*2pi*k/N}
        float2 X = cadd(A, cmul(Bv, e));
        arow[k] = X;
        if (k == 0)   // Nyquist bin: real
            arow[M2] = make_float2(A.x - Bv.x, 0.0f);
    }
}

// ---------- K_layer: einsum over i + irfft + gelu + (rfft | store h) ----------
// block = (b,o) row, 512 threads. Yh[k] = sum_i alpha[b,i,k]*G[l,o,i,k]
template<bool LAST>
__global__ __launch_bounds__(512) void k_apply_fft(
    const float2* __restrict__ alpha, const float2* __restrict__ G,
    const float* __restrict__ conv_b, float2* __restrict__ alpha_next,
    float2* __restrict__ hout, int layer)
{
    __shared__ float Yr[M2 + 2], Yi[M2 + 2];
    __shared__ float Ar[PADDED_M], Ai[PADDED_M], Br[PADDED_M], Bi[PADDED_M];
    int t = threadIdx.x;
    int row = blockIdx.x;            // b*32 + o
    int b = row >> 5, o = row & 31;
    const float2* abase = alpha + (size_t)(b * WW) * AST;
    const float2* gbase = G + (size_t)((layer * WW + o) * WW) * AST;

    float2 acc0 = make_float2(0.0f, 0.0f);
    float2 acc1 = make_float2(0.0f, 0.0f);
    #pragma unroll 4
    for (int i = 0; i < 32; ++i) {
        float2 a0 = abase[(size_t)i * AST + t];
        float2 g0 = gbase[(size_t)i * AST + t];
        float2 a1 = abase[(size_t)i * AST + t + 512];
        float2 g1 = gbase[(size_t)i * AST + t + 512];
        acc0.x = fmaf(a0.x, g0.x, fmaf(-a0.y, g0.y, acc0.x));
        acc0.y = fmaf(a0.x, g0.y, fmaf( a0.y, g0.x, acc0.y));
        acc1.x = fmaf(a1.x, g1.x, fmaf(-a1.y, g1.y, acc1.x));
        acc1.y = fmaf(a1.x, g1.y, fmaf( a1.y, g1.x, acc1.y));
    }
    // Nyquist: real dot over i, wave-0 shuffle reduce
    if (t < 64) {
        float p = 0.0f;
        if (t < 32)
            p = abase[(size_t)t * AST + M2].x * gbase[(size_t)t * AST + M2].x;
        #pragma unroll
        for (int off = 16; off >= 1; off >>= 1) p += __shfl_xor(p, off);
        if (t == 0) { Yr[M2] = p; Yi[M2] = 0.0f; }
    }
    if (t == 0) acc0.x += (float)NFFT * conv_b[layer * WW + o];
    Yr[t] = acc0.x;        Yi[t] = acc0.y;
    Yr[t + 512] = acc1.x;  Yi[t + 512] = acc1.y;
    __syncthreads();

    // irfft pack: Z[k] = A + iB from X[k], X[M2-k]
    #pragma unroll
    for (int j = 0; j < 2; ++j) {
        int k = t + j * 512;
        float2 Xk = make_float2(Yr[k], Yi[k]);
        float2 Xm = make_float2(Yr[M2 - k], Yi[M2 - k]);
        float2 A = make_float2(0.5f * (Xk.x + Xm.x), 0.5f * (Xk.y - Xm.y));
        float2 u = make_float2(Xk.x - Xm.x, Xk.y + Xm.y);
        float ph = (3.1415926535897932385f / (float)M2) * (float)k;
        float sn, cs;
        __sincosf(ph, &sn, &cs);
        float2 e = make_float2(cs, sn);            // e^{+i*2pi*k/N}
        float2 Bv = cmul(u, e);
        Ar[PAD(k)] = A.x - 0.5f * Bv.y;
        Ai[PAD(k)] = A.y + 0.5f * Bv.x;
    }
    __syncthreads();
    fft1024_g<1>(Ar, Ai, Br, Bi, t, t < 256);     // inverse -> B
    const float invM = 1.0f / (float)M2;
    if (LAST) {
        #pragma unroll
        for (int j = 0; j < 2; ++j) {
            int n = t + j * 512;
            float ge = gelu_f(Br[PAD(n)] * invM);
            float go = gelu_f(Bi[PAD(n)] * invM);
            hout[(size_t)row * M2 + n] = make_float2(ge, go);
        }
    } else {
        #pragma unroll
        for (int j = 0; j < 2; ++j) {
            int n = t + j * 512;
            float ge = gelu_f(Br[PAD(n)] * invM);
            float go = gelu_f(Bi[PAD(n)] * invM);
            Ar[PAD(n)] = ge;
            Ai[PAD(n)] = go;
        }
        __syncthreads();
        fft1024_g<-1>(Ar, Ai, Br, Bi, t, t < 256);
        unpack_store512(Br, Bi, alpha_next + (size_t)row * AST, t);
    }
}

// ---------- K5: head ----------
__global__ __launch_bounds__(256) void k_head(
    const float* __restrict__ h, const float* __restrict__ fc1_w,
    const float* __restrict__ fc1_b, const float* __restrict__ fc2_w,
    const float* __restrict__ fc2_b, float* __restrict__ out)
{
    __shared__ float s_w1[128 * 32];
    __shared__ float s_b1[128];
    __shared__ float s_w2[128];
    __shared__ float s_part[4][64];
    int t = threadIdx.x;
    for (int j = t; j < 128 * 32; j += 256) s_w1[j] = fc1_w[j];
    if (t < 128) { s_b1[t] = fc1_b[t]; s_w2[t] = fc2_w[t]; }
    __syncthreads();
    int wv  = t >> 6;                       // wave id = n-group
    int ln  = t & 63;
    int pos = blockIdx.x * 64 + ln;         // b*2048 + l
    int b = pos >> LOG2N, l = pos & (NFFT - 1);
    float hreg[32];
    #pragma unroll
    for (int w = 0; w < 32; ++w) hreg[w] = h[(b * WW + w) * NFFT + l];
    float acc = 0.0f;
    int n0 = wv * 32;
    for (int n = n0; n < n0 + 32; ++n) {
        float a = s_b1[n];
        #pragma unroll
        for (int w = 0; w < 32; w += 4) {
            float4 ww = *(const float4*)&s_w1[n * 32 + w];
            a = fmaf(ww.x, hreg[w],     a);
            a = fmaf(ww.y, hreg[w + 1], a);
            a = fmaf(ww.z, hreg[w + 2], a);
            a = fmaf(ww.w, hreg[w + 3], a);
        }
        acc = fmaf(s_w2[n], gelu_f(a), acc);
    }
    s_part[wv][ln] = acc;
    __syncthreads();
    if (t < 64) {
        float r = s_part[0][t] + s_part[1][t] + s_part[2][t] + s_part[3][t] + fc2_b[0];
        out[blockIdx.x * 64 + t] = r;
    }
}

extern "C" void kernel_launch(void* const* d_in, const int* in_sizes, int n_in,
                              void* d_out, int out_size, void* d_ws, size_t ws_size,
                              hipStream_t stream)
{
    const float* x       = (const float*)d_in[0];
    const float* tg      = (const float*)d_in[1];
    const float* fc0_w   = (const float*)d_in[2];
    const float* fc0_b   = (const float*)d_in[3];
    const float* pole_re = (const float*)d_in[4];
    const float* pole_im = (const float*)d_in[5];
    const float* res_re  = (const float*)d_in[6];
    const float* res_im  = (const float*)d_in[7];
    const float* spec_re = (const float*)d_in[8];
    const float* spec_im = (const float*)d_in[9];
    const float* conv_w  = (const float*)d_in[10];
    const float* conv_b  = (const float*)d_in[11];
    const float* fc1_w   = (const float*)d_in[12];
    const float* fc1_b   = (const float*)d_in[13];
    const float* fc2_w   = (const float*)d_in[14];
    const float* fc2_b   = (const float*)d_in[15];
    float* out = (float*)d_out;

    char* ws = (char*)d_ws;
    const size_t plane = (size_t)(BB * WW) * AST * sizeof(float2);   // 2.11 MiB
    float2* alphaA = (float2*)ws;
    float2* alphaB = (float2*)(ws + plane);
    float2* hbuf   = (float2*)(ws + 2 * plane);                      // 2 MiB
    float2* Gbuf   = (float2*)(ws + 3 * plane + (size_t)(BB * WW) * M2 * sizeof(float2));

    hipLaunchKernelGGL(k_genG_fc0, dim3(NLAYER * WW * WW + BB * WW), dim3(256), 0, stream,
                       pole_re, pole_im, res_re, res_im, spec_re, spec_im,
                       conv_w, tg, x, fc0_w, fc0_b, Gbuf, alphaA);
    float2* acur = alphaA;
    float2* anxt = alphaB;
    for (int layer = 0; layer < NLAYER; ++layer) {
        if (layer < NLAYER - 1)
            hipLaunchKernelGGL((k_apply_fft<false>), dim3(BB * WW), dim3(512), 0, stream,
                               acur, Gbuf, conv_b, anxt, (float2*)nullptr, layer);
        else
            hipLaunchKernelGGL((k_apply_fft<true>), dim3(BB * WW), dim3(512), 0, stream,
                               acur, Gbuf, conv_b, (float2*)nullptr, hbuf, layer);
        float2* tmp = acur; acur = anxt; anxt = tmp;
    }
    hipLaunchKernelGGL(k_head, dim3(BB * NFFT / 64), dim3(256), 0, stream,
                       (const float*)hbuf, fc1_w, fc1_b, fc2_w, fc2_b, out);
}

// Round 8
// 90.959 us; speedup vs baseline: 3.6613x; 1.1421x over previous
//
#include <hip/hip_runtime.h>
#include <math.h>

#define NFFT   2048
#define M2     1024
#define LOG2N  11
#define BB     8
#define WW     32
#define MM     16
#define NLAYER 4
#define AST    1032      // row stride (float2) for alpha / G half-spectra

// Padded LDS index (element-granular) for 1024-pt FFT arrays
#define PAD(i) ((i) + ((i) >> 5))
#define PADDED_M (M2 + (M2 >> 5))   // 1056

// ---------- fast gelu (exact-erf form, A&S 7.1.26, |err| <= 1.5e-7) ----------
__device__ __forceinline__ float gelu_f(float v) {
    float ax = fabsf(v) * 0.70710678118654752440f;
    float t  = __builtin_amdgcn_rcpf(fmaf(0.3275911f, ax, 1.0f));
    float s  = fmaf(1.061405429f, t, -1.453152027f);
    s = fmaf(s, t, 1.421413741f);
    s = fmaf(s, t, -0.284496736f);
    s = fmaf(s, t, 0.254829592f);
    s = s * t;
    float e  = __expf(-ax * ax);
    float er = fmaf(-s, e, 1.0f);          // erf(|v|/sqrt2)
    er = copysignf(er, v);
    return 0.5f * v * (1.0f + er);
}

// ---------- complex helpers ----------
__device__ __forceinline__ float2 cadd(float2 a, float2 b) { return make_float2(a.x + b.x, a.y + b.y); }
__device__ __forceinline__ float2 csub(float2 a, float2 b) { return make_float2(a.x - b.x, a.y - b.y); }
__device__ __forceinline__ float2 cmul(float2 a, float2 b) {
    return make_float2(fmaf(a.x, b.x, -a.y * b.y), fmaf(a.x, b.y, a.y * b.x));
}
template<int S> __device__ __forceinline__ float2 caddi(float2 a, float2 b) {
    return (S > 0) ? make_float2(a.x - b.y, a.y + b.x) : make_float2(a.x + b.y, a.y - b.x);
}
template<int S> __device__ __forceinline__ float2 csubi(float2 a, float2 b) {
    return (S > 0) ? make_float2(a.x + b.y, a.y - b.x) : make_float2(a.x - b.y, a.y + b.x);
}

template<int S> __device__ __forceinline__ void dft4(float2* a) {
    float2 t0 = cadd(a[0], a[2]), t1 = csub(a[0], a[2]);
    float2 t2 = cadd(a[1], a[3]), t3 = csub(a[1], a[3]);
    a[0] = cadd(t0, t2);
    a[2] = csub(t0, t2);
    a[1] = caddi<S>(t1, t3);
    a[3] = csubi<S>(t1, t3);
}

// ---------- Stockham radix-4 pass on float2 LDS, reg twiddle w1 ----------
// w1f is the FORWARD twiddle (cos, -sin) for this thread's s; S>0 conjugates.
template<int LS, int S>
__device__ __forceinline__ void pass_cx(const float2* src, float2* dst, int t, float2 w1f) {
    float2 a[4];
    #pragma unroll
    for (int r = 0; r < 4; ++r) a[r] = src[PAD(t + r * 256)];
    if (LS > 1) {
        float2 w1 = (S > 0) ? make_float2(w1f.x, -w1f.y) : w1f;
        float2 w2 = cmul(w1, w1);
        float2 w3 = cmul(w2, w1);
        a[1] = cmul(a[1], w1);
        a[2] = cmul(a[2], w2);
        a[3] = cmul(a[3], w3);
    }
    dft4<S>(a);
    int s = t & (LS - 1);
    int base = (t / LS) * (4 * LS) + s;
    #pragma unroll
    for (int r = 0; r < 4; ++r) dst[PAD(base + r * LS)] = a[r];
}

// Forward twiddles for the 4 twiddled passes, computed once per thread (t<256).
struct Tw { float2 t4, t16, t64, t256; };
__device__ __forceinline__ Tw make_tw(int t) {
    Tw w;
    float sn, cs;
    const float c0 = 6.2831853071795864769f;
    __sincosf(c0 * (float)(t & 3)   * (1.0f / 16.0f),   &sn, &cs); w.t4   = make_float2(cs, -sn);
    __sincosf(c0 * (float)(t & 15)  * (1.0f / 64.0f),   &sn, &cs); w.t16  = make_float2(cs, -sn);
    __sincosf(c0 * (float)(t & 63)  * (1.0f / 256.0f),  &sn, &cs); w.t64  = make_float2(cs, -sn);
    __sincosf(c0 * (float)(t & 255) * (1.0f / 1024.0f), &sn, &cs); w.t256 = make_float2(cs, -sn);
    return w;
}

// 1024-pt FFT: input natural order in A, output in B. act = (t < 256).
// Caller must __syncthreads() before calling.
template<int S>
__device__ __forceinline__ void fft1024_cx(float2* A, float2* B, int t, bool act, const Tw& w) {
    if (act) pass_cx<1,   S>(A, B, t, make_float2(1.0f, 0.0f));
    __syncthreads();
    if (act) pass_cx<4,   S>(B, A, t, w.t4);
    __syncthreads();
    if (act) pass_cx<16,  S>(A, B, t, w.t16);
    __syncthreads();
    if (act) pass_cx<64,  S>(B, A, t, w.t64);
    __syncthreads();
    if (act) pass_cx<256, S>(A, B, t, w.t256);
    __syncthreads();
}

// ---------- K_genG_fc0 ----------
// Blocks 0..1023: genG, wave-per-unit. unit u = blk*4 + wave; (l,o,i) from u.
// Each lane owns 16 bins k = lane + 64j. Modes outer, bins inner; imag
// accumulator defers the *omega to the end. Lane 0 handles Nyquist + DC.
// Blocks 1024..1279: fc0 + rfft for row = blk-1024.
__global__ __launch_bounds__(256) void k_genG_fc0(
    const float* __restrict__ pole_re, const float* __restrict__ pole_im,
    const float* __restrict__ res_re,  const float* __restrict__ res_im,
    const float* __restrict__ spec_re, const float* __restrict__ spec_im,
    const float* __restrict__ conv_w,  const float* __restrict__ tgrid,
    const float* __restrict__ x,       const float* __restrict__ fc0_w,
    const float* __restrict__ fc0_b,
    float2* __restrict__ G, float2* __restrict__ alpha)
{
    __shared__ float2 Acx[PADDED_M], Bcx[PADDED_M];
    int t = threadIdx.x;
    int blk = blockIdx.x;
    float dt = tgrid[1] - tgrid[0];
    float fscale = 6.2831853071795864769f / ((float)NFFT * dt);

    if (blk < NLAYER * WW * WW / 4) {
        // ---- genG: one (l,o,i) unit per wave ----
        int lane = t & 63;
        int u = blk * 4 + (t >> 6);
        int l = u >> 10, r = u & 1023, o = r >> 5, i = r & 31;
        int pb = ((l * WW + i) * WW + o) * MM;
        float cw = conv_w[(l * WW + o) * WW + i];
        float w2r[16];
        float2 acc[16];
        #pragma unroll
        for (int j = 0; j < 16; ++j) {
            float wv = fscale * (float)(lane + 64 * j);
            w2r[j] = wv * wv;
            acc[j] = make_float2(cw, 0.0f);
        }
        #pragma unroll
        for (int mq = 0; mq < 4; ++mq) {
            float4 P_re = *(const float4*)&pole_re[pb + 4 * mq];
            float4 P_im = *(const float4*)&pole_im[pb + 4 * mq];
            float4 R_re = *(const float4*)&res_re [pb + 4 * mq];
            float4 R_im = *(const float4*)&res_im [pb + 4 * mq];
            #pragma unroll
            for (int mm = 0; mm < 4; ++mm) {
                float Rp = (&P_re.x)[mm], Ip = (&P_im.x)[mm];
                float Rr = (&R_re.x)[mm], Ir = (&R_im.x)[mm];
                float b   = fmaf(Rr, Rp, Ir * Ip);      // Re(r * conj(p))
                float c   = fmaf(Rp, Rp, Ip * Ip);      // |p|^2
                float dd  = 2.0f * Rp;
                float dd2 = dd * dd;
                float add = Rr * dd;
                float bdd = b * dd;
                #pragma unroll
                for (int j = 0; j < 16; ++j) {
                    float uu  = c - w2r[j];
                    float inv = __builtin_amdgcn_rcpf(fmaf(dd2, w2r[j], uu * uu));
                    acc[j].x = fmaf(fmaf(add, w2r[j], b * uu), -inv, acc[j].x);
                    acc[j].y = fmaf(fmaf(Rr, uu, -bdd), inv, acc[j].y);  // *wv deferred
                }
            }
        }
        #pragma unroll
        for (int j = 0; j < 16; ++j)
            acc[j].y *= fscale * (float)(lane + 64 * j);
        if (lane < MM) {               // spectral-conv fold: bins k = lane < 16
            if (lane) {
                acc[0].x += spec_re[pb + lane];
                acc[0].y += spec_im[pb + lane];
            } else {
                acc[0].x += spec_re[pb];   // DC stays real (acc.y already 0)
            }
        }
        float2* grow = G + (size_t)((l * WW + o) * WW + i) * AST;
        #pragma unroll
        for (int j = 0; j < 16; ++j) grow[lane + 64 * j] = acc[j];
        if (lane == 0) {               // Nyquist: Re(H(w_nyq)), w negative
            float wn = -fscale * (float)M2;
            float accn = cw;
            #pragma unroll
            for (int mq = 0; mq < 4; ++mq) {
                float4 P_re = *(const float4*)&pole_re[pb + 4 * mq];
                float4 P_im = *(const float4*)&pole_im[pb + 4 * mq];
                float4 R_re = *(const float4*)&res_re [pb + 4 * mq];
                float4 R_im = *(const float4*)&res_im [pb + 4 * mq];
                #pragma unroll
                for (int mm = 0; mm < 4; ++mm) {
                    float Rp = (&P_re.x)[mm], Ip = (&P_im.x)[mm];
                    float Rr = (&R_re.x)[mm], Ir = (&R_im.x)[mm];
                    float e   = wn - Ip;
                    float num = fmaf(Ir, e, -(Rr * Rp));
                    float den = fmaf(e, e, Rp * Rp);
                    accn += num * __builtin_amdgcn_rcpf(den);
                }
            }
            grow[M2] = make_float2(accn, 0.0f);
        }
    } else {
        // ---- fc0 + rfft path ----
        int row = blk - NLAYER * WW * WW / 4;   // b*32 + w
        int b = row >> 5, w = row & 31;
        float w0 = fc0_w[2 * w], w1 = fc0_w[2 * w + 1], b0 = fc0_b[w];
        Tw tw = make_tw(t);
        const float2* x2 = (const float2*)(x + (size_t)b * NFFT);
        #pragma unroll
        for (int j = 0; j < 4; ++j) {
            int n = t + j * 256;
            float2 xv = x2[n];
            float g0 = (float)(2 * n)     * (1.0f / 2047.0f);
            float g1 = (float)(2 * n + 1) * (1.0f / 2047.0f);
            float v0 = gelu_f(fmaf(w0, xv.x, fmaf(w1, g0, b0)));
            float v1 = gelu_f(fmaf(w0, xv.y, fmaf(w1, g1, b0)));
            Acx[PAD(n)] = make_float2(v0, v1);   // z[n] = h[2n] + i h[2n+1]
        }
        __syncthreads();
        fft1024_cx<-1>(Acx, Bcx, t, true, tw);
        float2* arow = alpha + (size_t)row * AST;
        #pragma unroll
        for (int j = 0; j < 4; ++j) {
            int k  = t + j * 256;
            int mk = (M2 - k) & (M2 - 1);
            float2 Zk  = Bcx[PAD(k)];
            float2 Zmk = Bcx[PAD(mk)];
            float2 A  = make_float2(0.5f * (Zk.x + Zmk.x), 0.5f * (Zk.y - Zmk.y));
            float2 Bv = make_float2(0.5f * (Zk.y + Zmk.y), -0.5f * (Zk.x - Zmk.x));
            float ph = (3.1415926535897932385f / (float)M2) * (float)k;
            float sn, cs;
            __sincosf(ph, &sn, &cs);
            float2 e = make_float2(cs, -sn);           // e^{-i*2pi*k/N}
            float2 X = cadd(A, cmul(Bv, e));
            arow[k] = X;
            if (k == 0) arow[M2] = make_float2(A.x - Bv.x, 0.0f);
        }
    }
}

// ---------- K_layer: einsum over i + irfft + gelu + (rfft | store h) ----------
// block = (b,o) row, 512 threads. Yh[k] = sum_i alpha[b,i,k]*G[l,o,i,k]
template<bool LAST>
__global__ __launch_bounds__(512) void k_apply_fft(
    const float2* __restrict__ alpha, const float2* __restrict__ G,
    const float* __restrict__ conv_b, float2* __restrict__ alpha_next,
    float2* __restrict__ hout, int layer)
{
    __shared__ __align__(16) float2 Ycx[M2 + 2];
    __shared__ float2 Acx[PADDED_M], Bcx[PADDED_M];
    int t = threadIdx.x;
    int row = blockIdx.x;            // b*32 + o
    int b = row >> 5, o = row & 31;
    const float2* abase = alpha + (size_t)(b * WW) * AST;
    const float2* gbase = G + (size_t)((layer * WW + o) * WW) * AST;
    Tw tw;
    if (t < 256) tw = make_tw(t);

    // einsum: thread t owns bins 2t, 2t+1 -> float4 loads (16B)
    float2 acc0 = make_float2(0.0f, 0.0f);
    float2 acc1 = make_float2(0.0f, 0.0f);
    #pragma unroll 4
    for (int i = 0; i < 32; ++i) {
        const float4* ar = (const float4*)(abase + (size_t)i * AST);
        const float4* gr = (const float4*)(gbase + (size_t)i * AST);
        float4 av = ar[t];
        float4 gv = gr[t];
        acc0.x = fmaf(av.x, gv.x, fmaf(-av.y, gv.y, acc0.x));
        acc0.y = fmaf(av.x, gv.y, fmaf( av.y, gv.x, acc0.y));
        acc1.x = fmaf(av.z, gv.z, fmaf(-av.w, gv.w, acc1.x));
        acc1.y = fmaf(av.z, gv.w, fmaf( av.w, gv.z, acc1.y));
    }
    // Nyquist: real dot over i, wave-0 shuffle reduce
    if (t < 64) {
        float p = 0.0f;
        if (t < 32)
            p = abase[(size_t)t * AST + M2].x * gbase[(size_t)t * AST + M2].x;
        #pragma unroll
        for (int off = 16; off >= 1; off >>= 1) p += __shfl_xor(p, off);
        if (t == 0) Ycx[M2] = make_float2(p, 0.0f);
    }
    if (t == 0) acc0.x += (float)NFFT * conv_b[layer * WW + o];
    ((float4*)Ycx)[t] = make_float4(acc0.x, acc0.y, acc1.x, acc1.y);
    __syncthreads();

    // irfft pack: Z[k] = A + iB from X[k], X[M2-k]
    #pragma unroll
    for (int j = 0; j < 2; ++j) {
        int k = t + j * 512;
        float2 Xk = Ycx[k];
        float2 Xm = Ycx[M2 - k];
        float2 A = make_float2(0.5f * (Xk.x + Xm.x), 0.5f * (Xk.y - Xm.y));
        float2 u = make_float2(Xk.x - Xm.x, Xk.y + Xm.y);
        float ph = (3.1415926535897932385f / (float)M2) * (float)k;
        float sn, cs;
        __sincosf(ph, &sn, &cs);
        float2 e = make_float2(cs, sn);            // e^{+i*2pi*k/N}
        float2 Bv = cmul(u, e);
        Acx[PAD(k)] = make_float2(A.x - 0.5f * Bv.y, A.y + 0.5f * Bv.x);
    }
    __syncthreads();
    fft1024_cx<1>(Acx, Bcx, t, t < 256, tw);      // inverse -> B
    const float invM = 1.0f / (float)M2;
    if (LAST) {
        #pragma unroll
        for (int j = 0; j < 2; ++j) {
            int n = t + j * 512;
            float2 z = Bcx[PAD(n)];
            hout[(size_t)row * M2 + n] = make_float2(gelu_f(z.x * invM), gelu_f(z.y * invM));
        }
    } else {
        #pragma unroll
        for (int j = 0; j < 2; ++j) {
            int n = t + j * 512;
            float2 z = Bcx[PAD(n)];
            Acx[PAD(n)] = make_float2(gelu_f(z.x * invM), gelu_f(z.y * invM));
        }
        __syncthreads();
        fft1024_cx<-1>(Acx, Bcx, t, t < 256, tw);
        float2* arow = alpha_next + (size_t)row * AST;
        #pragma unroll
        for (int j = 0; j < 2; ++j) {
            int k  = t + j * 512;
            int mk = (M2 - k) & (M2 - 1);
            float2 Zk  = Bcx[PAD(k)];
            float2 Zmk = Bcx[PAD(mk)];
            float2 A  = make_float2(0.5f * (Zk.x + Zmk.x), 0.5f * (Zk.y - Zmk.y));
            float2 Bv = make_float2(0.5f * (Zk.y + Zmk.y), -0.5f * (Zk.x - Zmk.x));
            float ph = (3.1415926535897932385f / (float)M2) * (float)k;
            float sn, cs;
            __sincosf(ph, &sn, &cs);
            float2 e = make_float2(cs, -sn);       // e^{-i*2pi*k/N}
            float2 X = cadd(A, cmul(Bv, e));
            arow[k] = X;
            if (k == 0) arow[M2] = make_float2(A.x - Bv.x, 0.0f);
        }
    }
}

// ---------- K5: head ----------
__global__ __launch_bounds__(256) void k_head(
    const float* __restrict__ h, const float* __restrict__ fc1_w,
    const float* __restrict__ fc1_b, const float* __restrict__ fc2_w,
    const float* __restrict__ fc2_b, float* __restrict__ out)
{
    __shared__ float s_w1[128 * 32];
    __shared__ float s_b1[128];
    __shared__ float s_w2[128];
    __shared__ float s_part[4][64];
    int t = threadIdx.x;
    for (int j = t; j < 128 * 32; j += 256) s_w1[j] = fc1_w[j];
    if (t < 128) { s_b1[t] = fc1_b[t]; s_w2[t] = fc2_w[t]; }
    __syncthreads();
    int wv  = t >> 6;                       // wave id = n-group
    int ln  = t & 63;
    int pos = blockIdx.x * 64 + ln;         // b*2048 + l
    int b = pos >> LOG2N, l = pos & (NFFT - 1);
    float hreg[32];
    #pragma unroll
    for (int w = 0; w < 32; ++w) hreg[w] = h[(b * WW + w) * NFFT + l];
    float acc = 0.0f;
    int n0 = wv * 32;
    for (int n = n0; n < n0 + 32; ++n) {
        float a = s_b1[n];
        #pragma unroll
        for (int w = 0; w < 32; w += 4) {
            float4 ww = *(const float4*)&s_w1[n * 32 + w];
            a = fmaf(ww.x, hreg[w],     a);
            a = fmaf(ww.y, hreg[w + 1], a);
            a = fmaf(ww.z, hreg[w + 2], a);
            a = fmaf(ww.w, hreg[w + 3], a);
        }
        acc = fmaf(s_w2[n], gelu_f(a), acc);
    }
    s_part[wv][ln] = acc;
    __syncthreads();
    if (t < 64) {
        float r = s_part[0][t] + s_part[1][t] + s_part[2][t] + s_part[3][t] + fc2_b[0];
        out[blockIdx.x * 64 + t] = r;
    }
}

extern "C" void kernel_launch(void* const* d_in, const int* in_sizes, int n_in,
                              void* d_out, int out_size, void* d_ws, size_t ws_size,
                              hipStream_t stream)
{
    const float* x       = (const float*)d_in[0];
    const float* tg      = (const float*)d_in[1];
    const float* fc0_w   = (const float*)d_in[2];
    const float* fc0_b   = (const float*)d_in[3];
    const float* pole_re = (const float*)d_in[4];
    const float* pole_im = (const float*)d_in[5];
    const float* res_re  = (const float*)d_in[6];
    const float* res_im  = (const float*)d_in[7];
    const float* spec_re = (const float*)d_in[8];
    const float* spec_im = (const float*)d_in[9];
    const float* conv_w  = (const float*)d_in[10];
    const float* conv_b  = (const float*)d_in[11];
    const float* fc1_w   = (const float*)d_in[12];
    const float* fc1_b   = (const float*)d_in[13];
    const float* fc2_w   = (const float*)d_in[14];
    const float* fc2_b   = (const float*)d_in[15];
    float* out = (float*)d_out;

    char* ws = (char*)d_ws;
    const size_t plane = (size_t)(BB * WW) * AST * sizeof(float2);   // 2.11 MiB
    float2* alphaA = (float2*)ws;
    float2* alphaB = (float2*)(ws + plane);
    float2* hbuf   = (float2*)(ws + 2 * plane);                      // 2 MiB
    float2* Gbuf   = (float2*)(ws + 3 * plane);

    hipLaunchKernelGGL(k_genG_fc0, dim3(NLAYER * WW * WW / 4 + BB * WW), dim3(256), 0, stream,
                       pole_re, pole_im, res_re, res_im, spec_re, spec_im,
                       conv_w, tg, x, fc0_w, fc0_b, Gbuf, alphaA);
    float2* acur = alphaA;
    float2* anxt = alphaB;
    for (int layer = 0; layer < NLAYER; ++layer) {
        if (layer < NLAYER - 1)
            hipLaunchKernelGGL((k_apply_fft<false>), dim3(BB * WW), dim3(512), 0, stream,
                               acur, Gbuf, conv_b, anxt, (float2*)nullptr, layer);
        else
            hipLaunchKernelGGL((k_apply_fft<true>), dim3(BB * WW), dim3(512), 0, stream,
                               acur, Gbuf, conv_b, (float2*)nullptr, hbuf, layer);
        float2* tmp = acur; acur = anxt; anxt = tmp;
    }
    hipLaunchKernelGGL(k_head, dim3(BB * NFFT / 64), dim3(256), 0, stream,
                       (const float*)hbuf, fc1_w, fc1_b, fc2_w, fc2_b, out);
}